// Round 1
// baseline (77763.892 us; speedup 1.0000x reference)
//
#include <hip/hip_runtime.h>
#include <math.h>

#define NN 100000
#define NE 1000000
#define HD 64
#define NL 4
#define NG 64

__device__ __forceinline__ float sigmoidf_(float x) { return 1.0f / (1.0f + expf(-x)); }
__device__ __forceinline__ float siluf_(float x) { return x / (1.0f + expf(-x)); }

// h[n][j] = x[n] * in_w[j] + in_b[j]
__global__ void k_init_h(const float* __restrict__ x, const float* __restrict__ in_w,
                         const float* __restrict__ in_b, float* __restrict__ h) {
    int idx = blockIdx.x * blockDim.x + threadIdx.x;
    if (idx >= NN * HD) return;
    int n = idx >> 6, j = idx & 63;
    h[idx] = fmaf(x[n], in_w[j], in_b[j]);
}

// Coord update: per edge, delta = silu(cin@W1+b1)@W2+b2 ; CoorsNorm ; sigmoid gate ; atomicAdd into coords_next[row]
__global__ __launch_bounds__(256, 2)
void k_coord(const float* __restrict__ h,
             const float* __restrict__ ccur,
             float* __restrict__ cnext,
             const int* __restrict__ row, const int* __restrict__ col,
             const float* __restrict__ w1, const float* __restrict__ b1,
             const float* __restrict__ w2, const float* __restrict__ b2,
             const float* __restrict__ eww, const float* __restrict__ ewb,
             const float* __restrict__ cns) {
    __shared__ __attribute__((aligned(16))) float w1s[131 * 128];
    __shared__ __attribute__((aligned(16))) float w2s[128 * 3];
    __shared__ float b1s[128];
    for (int i = threadIdx.x; i < 131 * 128; i += blockDim.x) w1s[i] = w1[i];
    for (int i = threadIdx.x; i < 128 * 3; i += blockDim.x) w2s[i] = w2[i];
    if (threadIdx.x < 128) b1s[threadIdx.x] = b1[threadIdx.x];
    __syncthreads();

    int lane = threadIdx.x & 63;
    int wid = blockIdx.x * (blockDim.x >> 6) + (threadIdx.x >> 6);
    int nw = gridDim.x * (blockDim.x >> 6);

    float bb0 = b1s[2 * lane], bb1 = b1s[2 * lane + 1];
    float w2r[6];
#pragma unroll
    for (int d = 0; d < 3; ++d) {
        w2r[d]     = w2s[(2 * lane) * 3 + d];
        w2r[3 + d] = w2s[(2 * lane + 1) * 3 + d];
    }
    float e0 = eww[0], e1 = eww[1], e2 = eww[2], eb = ewb[0], sc = cns[0];
    float b20 = b2[0], b21 = b2[1], b22 = b2[2];
    const float2* w1s2 = (const float2*)w1s;

    for (int e = wid; e < NE; e += nw) {
        int r = row[e], c = col[e];
        float rx = ccur[r * 3 + 0] - ccur[c * 3 + 0];
        float ry = ccur[r * 3 + 1] - ccur[c * 3 + 1];
        float rz = ccur[r * 3 + 2] - ccur[c * 3 + 2];
        float hr = h[r * 64 + lane], hc = h[c * 64 + lane];
        float a0 = bb0, a1 = bb1;
#pragma unroll
        for (int k = 0; k < 64; ++k) {
            float v = __shfl(hr, k);
            float2 w = w1s2[k * 64 + lane];
            a0 = fmaf(v, w.x, a0); a1 = fmaf(v, w.y, a1);
        }
#pragma unroll
        for (int k = 0; k < 64; ++k) {
            float v = __shfl(hc, k);
            float2 w = w1s2[(64 + k) * 64 + lane];
            a0 = fmaf(v, w.x, a0); a1 = fmaf(v, w.y, a1);
        }
        {
            float2 w = w1s2[128 * 64 + lane]; a0 = fmaf(rx, w.x, a0); a1 = fmaf(rx, w.y, a1);
            w = w1s2[129 * 64 + lane];        a0 = fmaf(ry, w.x, a0); a1 = fmaf(ry, w.y, a1);
            w = w1s2[130 * 64 + lane];        a0 = fmaf(rz, w.x, a0); a1 = fmaf(rz, w.y, a1);
        }
        float s0 = siluf_(a0), s1 = siluf_(a1);
        float p0 = s0 * w2r[0] + s1 * w2r[3];
        float p1 = s0 * w2r[1] + s1 * w2r[4];
        float p2 = s0 * w2r[2] + s1 * w2r[5];
#pragma unroll
        for (int off = 32; off > 0; off >>= 1) {
            p0 += __shfl_xor(p0, off);
            p1 += __shfl_xor(p1, off);
            p2 += __shfl_xor(p2, off);
        }
        p0 += b20; p1 += b21; p2 += b22;
        float nrm = fmaxf(sqrtf(p0 * p0 + p1 * p1 + p2 * p2), 1e-8f);
        float g = sigmoidf_(fmaf(rx, e0, fmaf(ry, e1, fmaf(rz, e2, eb))));
        float m = sc / nrm * g;
        if (lane < 3) {
            float pd = (lane == 0) ? p0 : ((lane == 1) ? p1 : p2);
            atomicAdd(&cnext[r * 3 + lane], pd * m);
        }
    }
}

// Edge message: e = silu(silu(ein@W1+b1)@W2+b2) ; atomicAdd into agg[row]
__global__ __launch_bounds__(512, 2)
void k_edge(const float* __restrict__ h,
            const float* __restrict__ coords,
            float* __restrict__ agg,
            const int* __restrict__ row, const int* __restrict__ col,
            const float* __restrict__ w1, const float* __restrict__ b1,
            const float* __restrict__ w2, const float* __restrict__ b2) {
    __shared__ __attribute__((aligned(16))) float w1s[131 * 128];
    __shared__ __attribute__((aligned(16))) float w2s[128 * 64]; // pair layout [k][o][2]
    __shared__ float b1s[128];
    __shared__ float b2s[64];
    for (int i = threadIdx.x; i < 131 * 128; i += blockDim.x) w1s[i] = w1[i];
    for (int i = threadIdx.x; i < 128 * 64; i += blockDim.x) {
        int m = i >> 6, o = i & 63;
        w2s[(m >> 1) * 128 + o * 2 + (m & 1)] = w2[i];
    }
    if (threadIdx.x < 128) b1s[threadIdx.x] = b1[threadIdx.x];
    if (threadIdx.x < 64) b2s[threadIdx.x] = b2[threadIdx.x];
    __syncthreads();

    int lane = threadIdx.x & 63;
    int wid = blockIdx.x * (blockDim.x >> 6) + (threadIdx.x >> 6);
    int nw = gridDim.x * (blockDim.x >> 6);
    float bb0 = b1s[2 * lane], bb1 = b1s[2 * lane + 1], bo = b2s[lane];
    const float2* w1s2 = (const float2*)w1s;
    const float2* w2s2 = (const float2*)w2s;

    for (int e = wid; e < NE; e += nw) {
        int r = row[e], c = col[e];
        float rx = coords[r * 3 + 0] - coords[c * 3 + 0];
        float ry = coords[r * 3 + 1] - coords[c * 3 + 1];
        float rz = coords[r * 3 + 2] - coords[c * 3 + 2];
        float hr = h[r * 64 + lane], hc = h[c * 64 + lane];
        float a0 = bb0, a1 = bb1;
#pragma unroll
        for (int k = 0; k < 64; ++k) {
            float v = __shfl(hr, k);
            float2 w = w1s2[k * 64 + lane];
            a0 = fmaf(v, w.x, a0); a1 = fmaf(v, w.y, a1);
        }
#pragma unroll
        for (int k = 0; k < 64; ++k) {
            float v = __shfl(hc, k);
            float2 w = w1s2[(64 + k) * 64 + lane];
            a0 = fmaf(v, w.x, a0); a1 = fmaf(v, w.y, a1);
        }
        {
            float2 w = w1s2[128 * 64 + lane]; a0 = fmaf(rx, w.x, a0); a1 = fmaf(rx, w.y, a1);
            w = w1s2[129 * 64 + lane];        a0 = fmaf(ry, w.x, a0); a1 = fmaf(ry, w.y, a1);
            w = w1s2[130 * 64 + lane];        a0 = fmaf(rz, w.x, a0); a1 = fmaf(rz, w.y, a1);
        }
        float s0 = siluf_(a0), s1 = siluf_(a1);
        float acc = bo;
#pragma unroll
        for (int k = 0; k < 64; ++k) {
            float v0 = __shfl(s0, k), v1 = __shfl(s1, k);
            float2 w = w2s2[k * 64 + lane];
            acc = fmaf(v0, w.x, acc);
            acc = fmaf(v1, w.y, acc);
        }
        float eo = siluf_(acc);
        atomicAdd(&agg[r * 64 + lane], eo);
    }
}

// Node update: h = LN(h + silu([h,agg]@W1+b1)@W2+b2)
__global__ __launch_bounds__(512, 2)
void k_node(float* __restrict__ h, const float* __restrict__ agg,
            const float* __restrict__ w1, const float* __restrict__ b1,
            const float* __restrict__ w2, const float* __restrict__ b2) {
    __shared__ __attribute__((aligned(16))) float w1s[128 * 128];
    __shared__ __attribute__((aligned(16))) float w2s[128 * 64]; // pair layout
    __shared__ float b1s[128];
    __shared__ float b2s[64];
    for (int i = threadIdx.x; i < 128 * 128; i += blockDim.x) w1s[i] = w1[i];
    for (int i = threadIdx.x; i < 128 * 64; i += blockDim.x) {
        int m = i >> 6, o = i & 63;
        w2s[(m >> 1) * 128 + o * 2 + (m & 1)] = w2[i];
    }
    if (threadIdx.x < 128) b1s[threadIdx.x] = b1[threadIdx.x];
    if (threadIdx.x < 64) b2s[threadIdx.x] = b2[threadIdx.x];
    __syncthreads();

    int lane = threadIdx.x & 63;
    int wid = blockIdx.x * (blockDim.x >> 6) + (threadIdx.x >> 6);
    int nw = gridDim.x * (blockDim.x >> 6);
    float bb0 = b1s[2 * lane], bb1 = b1s[2 * lane + 1], bo = b2s[lane];
    const float2* w1s2 = (const float2*)w1s;
    const float2* w2s2 = (const float2*)w2s;

    for (int n = wid; n < NN; n += nw) {
        float hn = h[n * 64 + lane], an = agg[n * 64 + lane];
        float a0 = bb0, a1 = bb1;
#pragma unroll
        for (int k = 0; k < 64; ++k) {
            float v = __shfl(hn, k);
            float2 w = w1s2[k * 64 + lane];
            a0 = fmaf(v, w.x, a0); a1 = fmaf(v, w.y, a1);
        }
#pragma unroll
        for (int k = 0; k < 64; ++k) {
            float v = __shfl(an, k);
            float2 w = w1s2[(64 + k) * 64 + lane];
            a0 = fmaf(v, w.x, a0); a1 = fmaf(v, w.y, a1);
        }
        float s0 = siluf_(a0), s1 = siluf_(a1);
        float acc = bo;
#pragma unroll
        for (int k = 0; k < 64; ++k) {
            float v0 = __shfl(s0, k), v1 = __shfl(s1, k);
            float2 w = w2s2[k * 64 + lane];
            acc = fmaf(v0, w.x, acc);
            acc = fmaf(v1, w.y, acc);
        }
        float v = hn + acc;
        float sum = v, sq = v * v;
#pragma unroll
        for (int off = 32; off > 0; off >>= 1) {
            sum += __shfl_xor(sum, off);
            sq += __shfl_xor(sq, off);
        }
        float mu = sum * (1.0f / 64.0f);
        float var = sq * (1.0f / 64.0f) - mu * mu;
        h[n * 64 + lane] = (v - mu) * rsqrtf(var + 1e-5f);
    }
}

__global__ void k_pool(const float* __restrict__ h, const int* __restrict__ batch,
                       float* __restrict__ pooled, float* __restrict__ cnt) {
    int lane = threadIdx.x & 63;
    int wid = blockIdx.x * (blockDim.x >> 6) + (threadIdx.x >> 6);
    int nw = gridDim.x * (blockDim.x >> 6);
    for (int n = wid; n < NN; n += nw) {
        int b = batch[n];
        atomicAdd(&pooled[b * 64 + lane], h[n * 64 + lane]);
        if (lane == 0) atomicAdd(&cnt[b], 1.0f);
    }
}

__global__ void k_final(const float* __restrict__ pooled, const float* __restrict__ cnt,
                        const float* __restrict__ ow, const float* __restrict__ ob,
                        float* __restrict__ out) {
    __shared__ float red[2];
    int g = blockIdx.x, o = threadIdx.x; // 128 threads
    float c = fmaxf(cnt[g], 1.0f);
    float acc = ob[o];
#pragma unroll
    for (int j = 0; j < 64; ++j) {
        float pm = fmaxf(pooled[g * 64 + j] / c, 0.0f);
        acc = fmaf(pm, ow[j * 128 + o], acc);
    }
    float ss = acc * acc;
#pragma unroll
    for (int off = 32; off > 0; off >>= 1) ss += __shfl_xor(ss, off);
    if ((o & 63) == 0) red[o >> 6] = ss;
    __syncthreads();
    float nrm = sqrtf(red[0] + red[1]);
    out[g * 128 + o] = acc / fmaxf(nrm, 1e-12f);
}

extern "C" void kernel_launch(void* const* d_in, const int* in_sizes, int n_in,
                              void* d_out, int out_size, void* d_ws, size_t ws_size,
                              hipStream_t stream) {
    const float* x        = (const float*)d_in[0];
    const float* coords_in= (const float*)d_in[1];
    const float* in_w     = (const float*)d_in[2];
    const float* in_b     = (const float*)d_in[3];
    const float* coord_w1 = (const float*)d_in[4];
    const float* coord_b1 = (const float*)d_in[5];
    const float* coord_w2 = (const float*)d_in[6];
    const float* coord_b2 = (const float*)d_in[7];
    const float* ew_w     = (const float*)d_in[8];
    const float* ew_b     = (const float*)d_in[9];
    const float* cn_scale = (const float*)d_in[10];
    const float* edge_w1  = (const float*)d_in[11];
    const float* edge_b1  = (const float*)d_in[12];
    const float* edge_w2  = (const float*)d_in[13];
    const float* edge_b2  = (const float*)d_in[14];
    const float* node_w1  = (const float*)d_in[15];
    const float* node_b1  = (const float*)d_in[16];
    const float* node_w2  = (const float*)d_in[17];
    const float* node_b2  = (const float*)d_in[18];
    const float* out_w    = (const float*)d_in[19];
    const float* out_b    = (const float*)d_in[20];
    const int* ei         = (const int*)d_in[21];
    const int* batch      = (const int*)d_in[22];
    const int* row = ei;
    const int* col = ei + NE;

    float* ws = (float*)d_ws;
    float* h      = ws;                    // NN*64
    float* agg    = h + (size_t)NN * 64;   // NN*64
    float* cA     = agg + (size_t)NN * 64; // NN*3
    float* cB     = cA + (size_t)NN * 3;   // NN*3
    float* pooled = cB + (size_t)NN * 3;   // NG*64
    float* cnt    = pooled + NG * 64;      // NG

    k_init_h<<<(NN * HD + 255) / 256, 256, 0, stream>>>(x, in_w, in_b, h);

    const float* cur = coords_in;
    float* nxt = cA;
    for (int l = 0; l < NL; ++l) {
        hipMemcpyAsync(nxt, cur, (size_t)NN * 3 * sizeof(float), hipMemcpyDeviceToDevice, stream);
        k_coord<<<512, 256, 0, stream>>>(h, cur, nxt, row, col,
            coord_w1 + (size_t)l * 131 * 128, coord_b1 + l * 128,
            coord_w2 + (size_t)l * 128 * 3,  coord_b2 + l * 3,
            ew_w + l * 3, ew_b + l, cn_scale + l);
        hipMemsetAsync(agg, 0, (size_t)NN * 64 * sizeof(float), stream);
        k_edge<<<256, 512, 0, stream>>>(h, nxt, agg, row, col,
            edge_w1 + (size_t)l * 131 * 128, edge_b1 + l * 128,
            edge_w2 + (size_t)l * 128 * 64,  edge_b2 + l * 64);
        k_node<<<256, 512, 0, stream>>>(h, agg,
            node_w1 + (size_t)l * 128 * 128, node_b1 + l * 128,
            node_w2 + (size_t)l * 128 * 64,  node_b2 + l * 64);
        cur = nxt;
        nxt = (nxt == cA) ? cB : cA;
    }
    hipMemsetAsync(pooled, 0, (NG * 64 + NG) * sizeof(float), stream);
    k_pool<<<1024, 256, 0, stream>>>(h, batch, pooled, cnt);
    k_final<<<NG, 128, 0, stream>>>(pooled, cnt, out_w, out_b, (float*)d_out);
}

// Round 2
// 3879.317 us; speedup vs baseline: 20.0458x; 20.0458x over previous
//
#include <hip/hip_runtime.h>
#include <math.h>

#define NN 100000
#define NE 1000000
#define NG 64
#define NL 4

typedef __attribute__((ext_vector_type(8))) _Float16 f16x8;
typedef __attribute__((ext_vector_type(4))) float f32x4;

#define MFMA16(a, b, c) __builtin_amdgcn_mfma_f32_16x16x32_f16(a, b, c, 0, 0, 0)
#define LGKM0() asm volatile("s_waitcnt lgkmcnt(0)" ::: "memory")

__device__ __forceinline__ float sigmoidf_(float x) { return 1.0f / (1.0f + expf(-x)); }
__device__ __forceinline__ float siluf_(float x) { return x / (1.0f + expf(-x)); }

__global__ void k_init_h(const float* __restrict__ x, const float* __restrict__ in_w,
                         const float* __restrict__ in_b, float* __restrict__ h32,
                         _Float16* __restrict__ h16) {
    int idx = blockIdx.x * blockDim.x + threadIdx.x;
    if (idx >= NN * 64) return;
    int n = idx >> 6, j = idx & 63;
    float v = fmaf(x[n], in_w[j], in_b[j]);
    h32[idx] = v;
    h16[idx] = (_Float16)v;
}

// dst[o][k] = (k < K) ? src[k][o] : 0   (transpose + fp16 + zero-pad), dst stride SD
__global__ void k_prep_w(const float* __restrict__ src, _Float16* __restrict__ dst,
                         int K, int O, int SD) {
    int i = blockIdx.x * blockDim.x + threadIdx.x;
    if (i >= O * SD) return;
    int o = i / SD, k = i - o * SD;
    dst[i] = (k < K) ? (_Float16)src[(size_t)k * O + o] : (_Float16)0.0f;
}

// ---- coord kernel: GEMM1 (MFMA, K=131 padded to 160) + VALU 128->3 + CoorsNorm/gate/atomic
__global__ __launch_bounds__(256)
void k_coord_mfma(const _Float16* __restrict__ h16,
                  const float* __restrict__ ccur, float* __restrict__ cnext,
                  const int* __restrict__ row, const int* __restrict__ col,
                  const _Float16* __restrict__ w1T, const float* __restrict__ b1,
                  const float* __restrict__ w2, const float* __restrict__ b2,
                  const float* __restrict__ eww, const float* __restrict__ ewb,
                  const float* __restrict__ cns) {
    __shared__ _Float16 cinL[4][32][168];
    {
        _Float16* z = &cinL[0][0][0];
        for (int i = threadIdx.x; i < 4 * 32 * 168; i += 256) z[i] = (_Float16)0.0f;
    }
    __syncthreads();
    int w = threadIdx.x >> 6, lane = threadIdx.x & 63;
    int lc = lane & 15, lg = lane >> 4;
    float e0w = eww[0], e1w = eww[1], e2w = eww[2], ebw = ewb[0], sc = cns[0];
    float b20 = b2[0], b21 = b2[1], b22 = b2[2];
    _Float16(*ct)[168] = cinL[w];
    int wid = blockIdx.x * 4 + w, nw = gridDim.x * 4;

    for (int tile = wid; tile < NE / 32; tile += nw) {
        int e0 = tile * 32;
        {   // stage h[row] -> cols 0..63, h[col] -> cols 64..127 (2 lanes/edge)
            int e = e0 + (lane >> 1), part = lane & 1;
            int r = row[e], c = col[e];
            const f16x8* pr = (const f16x8*)(h16 + (size_t)r * 64 + part * 32);
            const f16x8* pc = (const f16x8*)(h16 + (size_t)c * 64 + part * 32);
            f16x8 r0 = pr[0], r1 = pr[1], r2 = pr[2], r3 = pr[3];
            f16x8 c0 = pc[0], c1 = pc[1], c2 = pc[2], c3 = pc[3];
            f16x8* dr = (f16x8*)&ct[lane >> 1][part * 32];
            dr[0] = r0; dr[1] = r1; dr[2] = r2; dr[3] = r3;
            f16x8* dc = (f16x8*)&ct[lane >> 1][64 + part * 32];
            dc[0] = c0; dc[1] = c1; dc[2] = c2; dc[3] = c3;
        }
        if (lane < 32) {  // rel (OLD coords) -> cols 128..130
            int e = e0 + lane;
            int r = row[e], c = col[e];
            ct[lane][128] = (_Float16)(ccur[r * 3 + 0] - ccur[c * 3 + 0]);
            ct[lane][129] = (_Float16)(ccur[r * 3 + 1] - ccur[c * 3 + 1]);
            ct[lane][130] = (_Float16)(ccur[r * 3 + 2] - ccur[c * 3 + 2]);
        }
        LGKM0();

        f32x4 acc[2][8];
#pragma unroll
        for (int rt = 0; rt < 2; ++rt)
#pragma unroll
            for (int t = 0; t < 8; ++t) acc[rt][t] = (f32x4){0.f, 0.f, 0.f, 0.f};
#pragma unroll
        for (int ks = 0; ks < 5; ++ks) {
            f16x8 a0 = *(const f16x8*)&ct[lc][ks * 32 + lg * 8];
            f16x8 a1 = *(const f16x8*)&ct[16 + lc][ks * 32 + lg * 8];
#pragma unroll
            for (int t = 0; t < 8; ++t) {
                f16x8 b = *(const f16x8*)&w1T[(size_t)(t * 16 + lc) * 168 + ks * 32 + lg * 8];
                acc[0][t] = MFMA16(a0, b, acc[0][t]);
                acc[1][t] = MFMA16(a1, b, acc[1][t]);
            }
        }
        // VALU GEMM2: partial[row][d] over this lane's 8 cols, then width-16 butterfly
        float p[8][3];
#pragma unroll
        for (int q = 0; q < 8; ++q) { p[q][0] = 0.f; p[q][1] = 0.f; p[q][2] = 0.f; }
#pragma unroll
        for (int t = 0; t < 8; ++t) {
            int colc = t * 16 + lc;
            float bias = b1[colc];
            float w20 = w2[colc * 3 + 0], w21 = w2[colc * 3 + 1], w22 = w2[colc * 3 + 2];
#pragma unroll
            for (int rt = 0; rt < 2; ++rt)
#pragma unroll
                for (int j = 0; j < 4; ++j) {
                    float s = siluf_(acc[rt][t][j] + bias);
                    int q = rt * 4 + j;
                    p[q][0] = fmaf(s, w20, p[q][0]);
                    p[q][1] = fmaf(s, w21, p[q][1]);
                    p[q][2] = fmaf(s, w22, p[q][2]);
                }
        }
#pragma unroll
        for (int m = 1; m < 16; m <<= 1)
#pragma unroll
            for (int q = 0; q < 8; ++q) {
                p[q][0] += __shfl_xor(p[q][0], m);
                p[q][1] += __shfl_xor(p[q][1], m);
                p[q][2] += __shfl_xor(p[q][2], m);
            }
        if ((lane & 15) < 8) {
            int q = lane & 7;
            int rloc = (q >> 2) * 16 + lg * 4 + (q & 3);
            float d0 = p[q][0] + b20, d1 = p[q][1] + b21, d2 = p[q][2] + b22;
            float nrm = fmaxf(sqrtf(d0 * d0 + d1 * d1 + d2 * d2), 1e-8f);
            float rx = (float)ct[rloc][128], ry = (float)ct[rloc][129], rz = (float)ct[rloc][130];
            float g = sigmoidf_(fmaf(rx, e0w, fmaf(ry, e1w, fmaf(rz, e2w, ebw))));
            float mm = sc / nrm * g;
            int r = row[e0 + rloc];
            atomicAdd(&cnext[r * 3 + 0], d0 * mm);
            atomicAdd(&cnext[r * 3 + 1], d1 * mm);
            atomicAdd(&cnext[r * 3 + 2], d2 * mm);
        }
    }
}

// ---- edge kernel: GEMM1 (131->128) + silu + GEMM2 (128->64) + silu + scatter-add
__global__ __launch_bounds__(256)
void k_edge_mfma(const _Float16* __restrict__ h16,
                 const float* __restrict__ coords, float* __restrict__ agg,
                 const int* __restrict__ row, const int* __restrict__ col,
                 const _Float16* __restrict__ w1T, const float* __restrict__ b1,
                 const _Float16* __restrict__ w2T, const float* __restrict__ b2) {
    __shared__ _Float16 cinL[4][32][168];
    {
        _Float16* z = &cinL[0][0][0];
        for (int i = threadIdx.x; i < 4 * 32 * 168; i += 256) z[i] = (_Float16)0.0f;
    }
    __syncthreads();
    int w = threadIdx.x >> 6, lane = threadIdx.x & 63;
    int lc = lane & 15, lg = lane >> 4;
    _Float16(*ct)[168] = cinL[w];
    int wid = blockIdx.x * 4 + w, nw = gridDim.x * 4;

    for (int tile = wid; tile < NE / 32; tile += nw) {
        int e0 = tile * 32;
        {
            int e = e0 + (lane >> 1), part = lane & 1;
            int r = row[e], c = col[e];
            const f16x8* pr = (const f16x8*)(h16 + (size_t)r * 64 + part * 32);
            const f16x8* pc = (const f16x8*)(h16 + (size_t)c * 64 + part * 32);
            f16x8 r0 = pr[0], r1 = pr[1], r2 = pr[2], r3 = pr[3];
            f16x8 c0 = pc[0], c1 = pc[1], c2 = pc[2], c3 = pc[3];
            f16x8* dr = (f16x8*)&ct[lane >> 1][part * 32];
            dr[0] = r0; dr[1] = r1; dr[2] = r2; dr[3] = r3;
            f16x8* dc = (f16x8*)&ct[lane >> 1][64 + part * 32];
            dc[0] = c0; dc[1] = c1; dc[2] = c2; dc[3] = c3;
        }
        if (lane < 32) {  // rel (NEW coords)
            int e = e0 + lane;
            int r = row[e], c = col[e];
            ct[lane][128] = (_Float16)(coords[r * 3 + 0] - coords[c * 3 + 0]);
            ct[lane][129] = (_Float16)(coords[r * 3 + 1] - coords[c * 3 + 1]);
            ct[lane][130] = (_Float16)(coords[r * 3 + 2] - coords[c * 3 + 2]);
        }
        LGKM0();

        f32x4 acc[2][8];
#pragma unroll
        for (int rt = 0; rt < 2; ++rt)
#pragma unroll
            for (int t = 0; t < 8; ++t) acc[rt][t] = (f32x4){0.f, 0.f, 0.f, 0.f};
#pragma unroll
        for (int ks = 0; ks < 5; ++ks) {
            f16x8 a0 = *(const f16x8*)&ct[lc][ks * 32 + lg * 8];
            f16x8 a1 = *(const f16x8*)&ct[16 + lc][ks * 32 + lg * 8];
#pragma unroll
            for (int t = 0; t < 8; ++t) {
                f16x8 b = *(const f16x8*)&w1T[(size_t)(t * 16 + lc) * 168 + ks * 32 + lg * 8];
                acc[0][t] = MFMA16(a0, b, acc[0][t]);
                acc[1][t] = MFMA16(a1, b, acc[1][t]);
            }
        }
        // silu -> back into cin tile (cols 0..127), wave-private so no barrier
#pragma unroll
        for (int t = 0; t < 8; ++t) {
            int colc = t * 16 + lc;
            float bias = b1[colc];
#pragma unroll
            for (int rt = 0; rt < 2; ++rt)
#pragma unroll
                for (int j = 0; j < 4; ++j)
                    ct[rt * 16 + lg * 4 + j][colc] = (_Float16)siluf_(acc[rt][t][j] + bias);
        }
        LGKM0();

        f32x4 acc2[2][4];
#pragma unroll
        for (int rt = 0; rt < 2; ++rt)
#pragma unroll
            for (int t = 0; t < 4; ++t) acc2[rt][t] = (f32x4){0.f, 0.f, 0.f, 0.f};
#pragma unroll
        for (int ks = 0; ks < 4; ++ks) {
            f16x8 a0 = *(const f16x8*)&ct[lc][ks * 32 + lg * 8];
            f16x8 a1 = *(const f16x8*)&ct[16 + lc][ks * 32 + lg * 8];
#pragma unroll
            for (int t = 0; t < 4; ++t) {
                f16x8 b = *(const f16x8*)&w2T[(size_t)(t * 16 + lc) * 136 + ks * 32 + lg * 8];
                acc2[0][t] = MFMA16(a0, b, acc2[0][t]);
                acc2[1][t] = MFMA16(a1, b, acc2[1][t]);
            }
        }
        int rr[8];
#pragma unroll
        for (int rt = 0; rt < 2; ++rt)
#pragma unroll
            for (int j = 0; j < 4; ++j) rr[rt * 4 + j] = row[e0 + rt * 16 + lg * 4 + j];
#pragma unroll
        for (int t = 0; t < 4; ++t) {
            int colc = t * 16 + lc;
            float bias = b2[colc];
#pragma unroll
            for (int rt = 0; rt < 2; ++rt)
#pragma unroll
                for (int j = 0; j < 4; ++j)
                    atomicAdd(&agg[(size_t)rr[rt * 4 + j] * 64 + colc],
                              siluf_(acc2[rt][t][j] + bias));
        }
    }
}

// ---- node kernel: GEMM1 ([h|agg] 128->128) + silu + GEMM2 (128->64) + residual + LN
__global__ __launch_bounds__(256)
void k_node_mfma(float* __restrict__ h32, _Float16* __restrict__ h16,
                 const float* __restrict__ agg,
                 const _Float16* __restrict__ w1T, const float* __restrict__ b1,
                 const _Float16* __restrict__ w2T, const float* __restrict__ b2) {
    __shared__ _Float16 cinL[4][32][136];
    int w = threadIdx.x >> 6, lane = threadIdx.x & 63;
    int lc = lane & 15, lg = lane >> 4;
    _Float16(*ct)[136] = cinL[w];
    int wid = blockIdx.x * 4 + w, nw = gridDim.x * 4;

    for (int tile = wid; tile < NN / 32; tile += nw) {
        int n0 = tile * 32;
        {
            int i = lane >> 1, part = lane & 1;
            int n = n0 + i;
            const f16x8* ph = (const f16x8*)(h16 + (size_t)n * 64 + part * 32);
            f16x8 h0 = ph[0], h1 = ph[1], h2 = ph[2], h3 = ph[3];
            f16x8* dh = (f16x8*)&ct[i][part * 32];
            dh[0] = h0; dh[1] = h1; dh[2] = h2; dh[3] = h3;
            const f32x4* pa = (const f32x4*)(agg + (size_t)n * 64 + part * 32);
            f16x8* da = (f16x8*)&ct[i][64 + part * 32];
#pragma unroll
            for (int v2 = 0; v2 < 4; ++v2) {
                f32x4 xx = pa[2 * v2], yy = pa[2 * v2 + 1];
                f16x8 o;
                o[0] = (_Float16)xx[0]; o[1] = (_Float16)xx[1];
                o[2] = (_Float16)xx[2]; o[3] = (_Float16)xx[3];
                o[4] = (_Float16)yy[0]; o[5] = (_Float16)yy[1];
                o[6] = (_Float16)yy[2]; o[7] = (_Float16)yy[3];
                da[v2] = o;
            }
        }
        LGKM0();

        f32x4 acc[2][8];
#pragma unroll
        for (int rt = 0; rt < 2; ++rt)
#pragma unroll
            for (int t = 0; t < 8; ++t) acc[rt][t] = (f32x4){0.f, 0.f, 0.f, 0.f};
#pragma unroll
        for (int ks = 0; ks < 4; ++ks) {
            f16x8 a0 = *(const f16x8*)&ct[lc][ks * 32 + lg * 8];
            f16x8 a1 = *(const f16x8*)&ct[16 + lc][ks * 32 + lg * 8];
#pragma unroll
            for (int t = 0; t < 8; ++t) {
                f16x8 b = *(const f16x8*)&w1T[(size_t)(t * 16 + lc) * 136 + ks * 32 + lg * 8];
                acc[0][t] = MFMA16(a0, b, acc[0][t]);
                acc[1][t] = MFMA16(a1, b, acc[1][t]);
            }
        }
#pragma unroll
        for (int t = 0; t < 8; ++t) {
            int colc = t * 16 + lc;
            float bias = b1[colc];
#pragma unroll
            for (int rt = 0; rt < 2; ++rt)
#pragma unroll
                for (int j = 0; j < 4; ++j)
                    ct[rt * 16 + lg * 4 + j][colc] = (_Float16)siluf_(acc[rt][t][j] + bias);
        }
        LGKM0();

        f32x4 acc2[2][4];
#pragma unroll
        for (int rt = 0; rt < 2; ++rt)
#pragma unroll
            for (int t = 0; t < 4; ++t) acc2[rt][t] = (f32x4){0.f, 0.f, 0.f, 0.f};
#pragma unroll
        for (int ks = 0; ks < 4; ++ks) {
            f16x8 a0 = *(const f16x8*)&ct[lc][ks * 32 + lg * 8];
            f16x8 a1 = *(const f16x8*)&ct[16 + lc][ks * 32 + lg * 8];
#pragma unroll
            for (int t = 0; t < 4; ++t) {
                f16x8 b = *(const f16x8*)&w2T[(size_t)(t * 16 + lc) * 136 + ks * 32 + lg * 8];
                acc2[0][t] = MFMA16(a0, b, acc2[0][t]);
                acc2[1][t] = MFMA16(a1, b, acc2[1][t]);
            }
        }
        // residual + LN over 64 cols (each lane holds 4 cols x 8 rows)
        float vv[2][4][4], sums[8], sqs[8];
#pragma unroll
        for (int q = 0; q < 8; ++q) { sums[q] = 0.f; sqs[q] = 0.f; }
#pragma unroll
        for (int rt = 0; rt < 2; ++rt)
#pragma unroll
            for (int t = 0; t < 4; ++t) {
                int colc = t * 16 + lc;
                float bias = b2[colc];
#pragma unroll
                for (int j = 0; j < 4; ++j) {
                    int rloc = rt * 16 + lg * 4 + j;
                    float val = h32[(size_t)(n0 + rloc) * 64 + colc] + acc2[rt][t][j] + bias;
                    vv[rt][t][j] = val;
                    sums[rt * 4 + j] += val;
                    sqs[rt * 4 + j] += val * val;
                }
            }
#pragma unroll
        for (int m = 1; m < 16; m <<= 1)
#pragma unroll
            for (int q = 0; q < 8; ++q) {
                sums[q] += __shfl_xor(sums[q], m);
                sqs[q] += __shfl_xor(sqs[q], m);
            }
#pragma unroll
        for (int rt = 0; rt < 2; ++rt)
#pragma unroll
            for (int j = 0; j < 4; ++j) {
                int q = rt * 4 + j;
                float mu = sums[q] * (1.0f / 64.0f);
                float var = sqs[q] * (1.0f / 64.0f) - mu * mu;
                float rs = rsqrtf(var + 1e-5f);
#pragma unroll
                for (int t = 0; t < 4; ++t) {
                    int colc = t * 16 + lc;
                    int rloc = rt * 16 + lg * 4 + j;
                    float out = (vv[rt][t][j] - mu) * rs;
                    size_t idx = (size_t)(n0 + rloc) * 64 + colc;
                    h32[idx] = out;
                    h16[idx] = (_Float16)out;
                }
            }
    }
}

__global__ void k_pool(const float* __restrict__ h, const int* __restrict__ batch,
                       float* __restrict__ pooled, float* __restrict__ cnt) {
    int lane = threadIdx.x & 63;
    int wid = blockIdx.x * (blockDim.x >> 6) + (threadIdx.x >> 6);
    int nw = gridDim.x * (blockDim.x >> 6);
    for (int n = wid; n < NN; n += nw) {
        int b = batch[n];
        atomicAdd(&pooled[b * 64 + lane], h[n * 64 + lane]);
        if (lane == 0) atomicAdd(&cnt[b], 1.0f);
    }
}

__global__ void k_final(const float* __restrict__ pooled, const float* __restrict__ cnt,
                        const float* __restrict__ ow, const float* __restrict__ ob,
                        float* __restrict__ out) {
    __shared__ float red[2];
    int g = blockIdx.x, o = threadIdx.x;  // 128 threads
    float c = fmaxf(cnt[g], 1.0f);
    float acc = ob[o];
#pragma unroll
    for (int j = 0; j < 64; ++j) {
        float pm = fmaxf(pooled[g * 64 + j] / c, 0.0f);
        acc = fmaf(pm, ow[j * 128 + o], acc);
    }
    float ss = acc * acc;
#pragma unroll
    for (int off = 32; off > 0; off >>= 1) ss += __shfl_xor(ss, off);
    if ((o & 63) == 0) red[o >> 6] = ss;
    __syncthreads();
    float nrm = sqrtf(red[0] + red[1]);
    out[g * 128 + o] = acc / fmaxf(nrm, 1e-12f);
}

extern "C" void kernel_launch(void* const* d_in, const int* in_sizes, int n_in,
                              void* d_out, int out_size, void* d_ws, size_t ws_size,
                              hipStream_t stream) {
    const float* x         = (const float*)d_in[0];
    const float* coords_in = (const float*)d_in[1];
    const float* in_w      = (const float*)d_in[2];
    const float* in_b      = (const float*)d_in[3];
    const float* coord_w1  = (const float*)d_in[4];
    const float* coord_b1  = (const float*)d_in[5];
    const float* coord_w2  = (const float*)d_in[6];
    const float* coord_b2  = (const float*)d_in[7];
    const float* ew_w      = (const float*)d_in[8];
    const float* ew_b      = (const float*)d_in[9];
    const float* cn_scale  = (const float*)d_in[10];
    const float* edge_w1   = (const float*)d_in[11];
    const float* edge_b1   = (const float*)d_in[12];
    const float* edge_w2   = (const float*)d_in[13];
    const float* edge_b2   = (const float*)d_in[14];
    const float* node_w1   = (const float*)d_in[15];
    const float* node_b1   = (const float*)d_in[16];
    const float* node_w2   = (const float*)d_in[17];
    const float* node_b2   = (const float*)d_in[18];
    const float* out_w     = (const float*)d_in[19];
    const float* out_b     = (const float*)d_in[20];
    const int* ei          = (const int*)d_in[21];
    const int* batch       = (const int*)d_in[22];
    const int* row = ei;
    const int* col = ei + NE;

    char* wp = (char*)d_ws;
    float* h32    = (float*)wp; wp += (size_t)NN * 64 * 4;
    float* agg    = (float*)wp; wp += (size_t)NN * 64 * 4;
    float* cA     = (float*)wp; wp += (size_t)NN * 3 * 4;
    float* cB     = (float*)wp; wp += (size_t)NN * 3 * 4;
    float* pooled = (float*)wp; wp += (size_t)NG * 64 * 4;
    float* cnt    = (float*)wp; wp += (size_t)NG * 4;
    _Float16* h16  = (_Float16*)wp; wp += (size_t)NN * 64 * 2;
    _Float16* cw1T = (_Float16*)wp; wp += (size_t)NL * 128 * 168 * 2;
    _Float16* ew1T = (_Float16*)wp; wp += (size_t)NL * 128 * 168 * 2;
    _Float16* ew2T = (_Float16*)wp; wp += (size_t)NL * 64 * 136 * 2;
    _Float16* nw1T = (_Float16*)wp; wp += (size_t)NL * 128 * 136 * 2;
    _Float16* nw2T = (_Float16*)wp; wp += (size_t)NL * 64 * 136 * 2;

    for (int l = 0; l < NL; ++l) {
        k_prep_w<<<(128 * 168 + 255) / 256, 256, 0, stream>>>(
            coord_w1 + (size_t)l * 131 * 128, cw1T + (size_t)l * 128 * 168, 131, 128, 168);
        k_prep_w<<<(128 * 168 + 255) / 256, 256, 0, stream>>>(
            edge_w1 + (size_t)l * 131 * 128, ew1T + (size_t)l * 128 * 168, 131, 128, 168);
        k_prep_w<<<(64 * 136 + 255) / 256, 256, 0, stream>>>(
            edge_w2 + (size_t)l * 128 * 64, ew2T + (size_t)l * 64 * 136, 128, 64, 136);
        k_prep_w<<<(128 * 136 + 255) / 256, 256, 0, stream>>>(
            node_w1 + (size_t)l * 128 * 128, nw1T + (size_t)l * 128 * 136, 128, 128, 136);
        k_prep_w<<<(64 * 136 + 255) / 256, 256, 0, stream>>>(
            node_w2 + (size_t)l * 128 * 64, nw2T + (size_t)l * 64 * 136, 128, 64, 136);
    }
    k_init_h<<<(NN * 64 + 255) / 256, 256, 0, stream>>>(x, in_w, in_b, h32, h16);

    const float* cur = coords_in;
    float* nxt = cA;
    for (int l = 0; l < NL; ++l) {
        hipMemcpyAsync(nxt, cur, (size_t)NN * 3 * sizeof(float), hipMemcpyDeviceToDevice, stream);
        k_coord_mfma<<<2048, 256, 0, stream>>>(h16, cur, nxt, row, col,
            cw1T + (size_t)l * 128 * 168, coord_b1 + l * 128,
            coord_w2 + (size_t)l * 128 * 3, coord_b2 + l * 3,
            ew_w + l * 3, ew_b + l, cn_scale + l);
        hipMemsetAsync(agg, 0, (size_t)NN * 64 * sizeof(float), stream);
        k_edge_mfma<<<2048, 256, 0, stream>>>(h16, nxt, agg, row, col,
            ew1T + (size_t)l * 128 * 168, edge_b1 + l * 128,
            ew2T + (size_t)l * 64 * 136, edge_b2 + l * 64);
        k_node_mfma<<<782, 256, 0, stream>>>(h32, h16, agg,
            nw1T + (size_t)l * 128 * 136, node_b1 + l * 128,
            nw2T + (size_t)l * 64 * 136, node_b2 + l * 64);
        cur = nxt;
        nxt = (nxt == cA) ? cB : cA;
    }
    hipMemsetAsync(pooled, 0, (size_t)(NG * 64 + NG) * sizeof(float), stream);
    k_pool<<<1024, 256, 0, stream>>>(h32, batch, pooled, cnt);
    k_final<<<NG, 128, 0, stream>>>(pooled, cnt, out_w, out_b, (float*)d_out);
}

// Round 3
// 3040.914 us; speedup vs baseline: 25.5725x; 1.2757x over previous
//
#include <hip/hip_runtime.h>
#include <math.h>

#define NN 100000
#define NE 1000000
#define NG 64
#define NL 4

typedef __attribute__((ext_vector_type(8))) _Float16 f16x8;
typedef __attribute__((ext_vector_type(4))) float f32x4;

#define MFMA16(a, b, c) __builtin_amdgcn_mfma_f32_16x16x32_f16(a, b, c, 0, 0, 0)
#define LGKM0() asm volatile("s_waitcnt lgkmcnt(0)" ::: "memory")

__device__ __forceinline__ float sigmoidf_(float x) { return 1.0f / (1.0f + expf(-x)); }
__device__ __forceinline__ float siluf_(float x) { return x / (1.0f + expf(-x)); }

__global__ void k_init_h(const float* __restrict__ x, const float* __restrict__ in_w,
                         const float* __restrict__ in_b, float* __restrict__ h32,
                         _Float16* __restrict__ h16) {
    int idx = blockIdx.x * blockDim.x + threadIdx.x;
    if (idx >= NN * 64) return;
    int n = idx >> 6, j = idx & 63;
    float v = fmaf(x[n], in_w[j], in_b[j]);
    h32[idx] = v;
    h16[idx] = (_Float16)v;
}

// One fused prep: transpose + fp16 + zero-pad all 5 weight families x 4 layers.
// dst[o][k] = (k < K) ? src[k][O_cnt... ] : 0
#define SEG0 21504  // 128*168 cw1T (K=131,O=128,SD=168)
#define SEG1 21504  // ew1T
#define SEG2 8704   // 64*136  ew2T (K=128,O=64, SD=136)
#define SEG3 17408  // 128*136 nw1T (K=128,O=128,SD=136)
#define SEG4 8704   // nw2T
#define SEGTOT (SEG0 + SEG1 + SEG2 + SEG3 + SEG4)
__global__ void k_prep_all(const float* __restrict__ cw1, const float* __restrict__ ew1,
                           const float* __restrict__ ew2, const float* __restrict__ nw1,
                           const float* __restrict__ nw2,
                           _Float16* __restrict__ cw1T, _Float16* __restrict__ ew1T,
                           _Float16* __restrict__ ew2T, _Float16* __restrict__ nw1T,
                           _Float16* __restrict__ nw2T) {
    int i = blockIdx.x * blockDim.x + threadIdx.x;
    if (i >= NL * SEGTOT) return;
    int l = i / SEGTOT, r = i - l * SEGTOT;
    const float* src; _Float16* dst; int K, O, SD, j;
    if (r < SEG0) { src = cw1 + (size_t)l * 131 * 128; dst = cw1T + (size_t)l * SEG0; K = 131; O = 128; SD = 168; j = r; }
    else if ((r -= SEG0) < SEG1) { src = ew1 + (size_t)l * 131 * 128; dst = ew1T + (size_t)l * SEG1; K = 131; O = 128; SD = 168; j = r; }
    else if ((r -= SEG1) < SEG2) { src = ew2 + (size_t)l * 128 * 64; dst = ew2T + (size_t)l * SEG2; K = 128; O = 64; SD = 136; j = r; }
    else if ((r -= SEG2) < SEG3) { src = nw1 + (size_t)l * 128 * 128; dst = nw1T + (size_t)l * SEG3; K = 128; O = 128; SD = 136; j = r; }
    else { r -= SEG3; src = nw2 + (size_t)l * 128 * 64; dst = nw2T + (size_t)l * SEG4; K = 128; O = 64; SD = 136; j = r; }
    int o = j / SD, k = j - o * SD;
    dst[j] = (k < K) ? (_Float16)src[(size_t)k * O + o] : (_Float16)0.0f;
}

// ---- coord kernel: GEMM1 (MFMA, K=131 padded to 160) + VALU 128->3 + CoorsNorm/gate/atomic
__global__ __launch_bounds__(256)
void k_coord_mfma(const _Float16* __restrict__ h16,
                  const float* __restrict__ ccur, float* __restrict__ cnext,
                  const int* __restrict__ row, const int* __restrict__ col,
                  const _Float16* __restrict__ w1T, const float* __restrict__ b1,
                  const float* __restrict__ w2, const float* __restrict__ b2,
                  const float* __restrict__ eww, const float* __restrict__ ewb,
                  const float* __restrict__ cns) {
    __shared__ _Float16 cinL[4][32][168];
    {
        _Float16* z = &cinL[0][0][0];
        for (int i = threadIdx.x; i < 4 * 32 * 168; i += 256) z[i] = (_Float16)0.0f;
    }
    __syncthreads();
    int w = threadIdx.x >> 6, lane = threadIdx.x & 63;
    int lc = lane & 15, lg = lane >> 4;
    float e0w = eww[0], e1w = eww[1], e2w = eww[2], ebw = ewb[0], sc = cns[0];
    float b20 = b2[0], b21 = b2[1], b22 = b2[2];
    _Float16(*ct)[168] = cinL[w];
    int wid = blockIdx.x * 4 + w, nw = gridDim.x * 4;

    for (int tile = wid; tile < NE / 32; tile += nw) {
        int e0 = tile * 32;
        {   // stage h[row] -> cols 0..63, h[col] -> cols 64..127 (2 lanes/edge)
            int e = e0 + (lane >> 1), part = lane & 1;
            int r = row[e], c = col[e];
            const f16x8* pr = (const f16x8*)(h16 + (size_t)r * 64 + part * 32);
            const f16x8* pc = (const f16x8*)(h16 + (size_t)c * 64 + part * 32);
            f16x8 r0 = pr[0], r1 = pr[1], r2 = pr[2], r3 = pr[3];
            f16x8 c0 = pc[0], c1 = pc[1], c2 = pc[2], c3 = pc[3];
            f16x8* dr = (f16x8*)&ct[lane >> 1][part * 32];
            dr[0] = r0; dr[1] = r1; dr[2] = r2; dr[3] = r3;
            f16x8* dc = (f16x8*)&ct[lane >> 1][64 + part * 32];
            dc[0] = c0; dc[1] = c1; dc[2] = c2; dc[3] = c3;
        }
        if (lane < 32) {  // rel (OLD coords) -> cols 128..130
            int e = e0 + lane;
            int r = row[e], c = col[e];
            ct[lane][128] = (_Float16)(ccur[r * 3 + 0] - ccur[c * 3 + 0]);
            ct[lane][129] = (_Float16)(ccur[r * 3 + 1] - ccur[c * 3 + 1]);
            ct[lane][130] = (_Float16)(ccur[r * 3 + 2] - ccur[c * 3 + 2]);
        }
        LGKM0();

        f32x4 acc[2][8];
#pragma unroll
        for (int rt = 0; rt < 2; ++rt)
#pragma unroll
            for (int t = 0; t < 8; ++t) acc[rt][t] = (f32x4){0.f, 0.f, 0.f, 0.f};
#pragma unroll
        for (int ks = 0; ks < 5; ++ks) {
            f16x8 a0 = *(const f16x8*)&ct[lc][ks * 32 + lg * 8];
            f16x8 a1 = *(const f16x8*)&ct[16 + lc][ks * 32 + lg * 8];
#pragma unroll
            for (int t = 0; t < 8; ++t) {
                f16x8 b = *(const f16x8*)&w1T[(size_t)(t * 16 + lc) * 168 + ks * 32 + lg * 8];
                acc[0][t] = MFMA16(a0, b, acc[0][t]);
                acc[1][t] = MFMA16(a1, b, acc[1][t]);
            }
        }
        // VALU GEMM2: partial[row][d] over this lane's 8 cols, then width-16 butterfly
        float p[8][3];
#pragma unroll
        for (int q = 0; q < 8; ++q) { p[q][0] = 0.f; p[q][1] = 0.f; p[q][2] = 0.f; }
#pragma unroll
        for (int t = 0; t < 8; ++t) {
            int colc = t * 16 + lc;
            float bias = b1[colc];
            float w20 = w2[colc * 3 + 0], w21 = w2[colc * 3 + 1], w22 = w2[colc * 3 + 2];
#pragma unroll
            for (int rt = 0; rt < 2; ++rt)
#pragma unroll
                for (int j = 0; j < 4; ++j) {
                    float s = siluf_(acc[rt][t][j] + bias);
                    int q = rt * 4 + j;
                    p[q][0] = fmaf(s, w20, p[q][0]);
                    p[q][1] = fmaf(s, w21, p[q][1]);
                    p[q][2] = fmaf(s, w22, p[q][2]);
                }
        }
#pragma unroll
        for (int m = 1; m < 16; m <<= 1)
#pragma unroll
            for (int q = 0; q < 8; ++q) {
                p[q][0] += __shfl_xor(p[q][0], m);
                p[q][1] += __shfl_xor(p[q][1], m);
                p[q][2] += __shfl_xor(p[q][2], m);
            }
        if ((lane & 15) < 8) {
            int q = lane & 7;
            int rloc = (q >> 2) * 16 + lg * 4 + (q & 3);
            float d0 = p[q][0] + b20, d1 = p[q][1] + b21, d2 = p[q][2] + b22;
            float nrm = fmaxf(sqrtf(d0 * d0 + d1 * d1 + d2 * d2), 1e-8f);
            float rx = (float)ct[rloc][128], ry = (float)ct[rloc][129], rz = (float)ct[rloc][130];
            float g = sigmoidf_(fmaf(rx, e0w, fmaf(ry, e1w, fmaf(rz, e2w, ebw))));
            float mm = sc / nrm * g;
            int r = row[e0 + rloc];
            atomicAdd(&cnext[r * 3 + 0], d0 * mm);
            atomicAdd(&cnext[r * 3 + 1], d1 * mm);
            atomicAdd(&cnext[r * 3 + 2], d2 * mm);
        }
    }
}

// ---- edge kernel: GEMM1 (131->128) + silu + GEMM2 (128->64) + silu + scatter-add
__global__ __launch_bounds__(256)
void k_edge_mfma(const _Float16* __restrict__ h16,
                 const float* __restrict__ coords, float* __restrict__ agg,
                 const int* __restrict__ row, const int* __restrict__ col,
                 const _Float16* __restrict__ w1T, const float* __restrict__ b1,
                 const _Float16* __restrict__ w2T, const float* __restrict__ b2) {
    __shared__ _Float16 cinL[4][32][168];
    {
        _Float16* z = &cinL[0][0][0];
        for (int i = threadIdx.x; i < 4 * 32 * 168; i += 256) z[i] = (_Float16)0.0f;
    }
    __syncthreads();
    int w = threadIdx.x >> 6, lane = threadIdx.x & 63;
    int lc = lane & 15, lg = lane >> 4;
    _Float16(*ct)[168] = cinL[w];
    int wid = blockIdx.x * 4 + w, nw = gridDim.x * 4;

    for (int tile = wid; tile < NE / 32; tile += nw) {
        int e0 = tile * 32;
        {
            int e = e0 + (lane >> 1), part = lane & 1;
            int r = row[e], c = col[e];
            const f16x8* pr = (const f16x8*)(h16 + (size_t)r * 64 + part * 32);
            const f16x8* pc = (const f16x8*)(h16 + (size_t)c * 64 + part * 32);
            f16x8 r0 = pr[0], r1 = pr[1], r2 = pr[2], r3 = pr[3];
            f16x8 c0 = pc[0], c1 = pc[1], c2 = pc[2], c3 = pc[3];
            f16x8* dr = (f16x8*)&ct[lane >> 1][part * 32];
            dr[0] = r0; dr[1] = r1; dr[2] = r2; dr[3] = r3;
            f16x8* dc = (f16x8*)&ct[lane >> 1][64 + part * 32];
            dc[0] = c0; dc[1] = c1; dc[2] = c2; dc[3] = c3;
        }
        if (lane < 32) {  // rel (NEW coords)
            int e = e0 + lane;
            int r = row[e], c = col[e];
            ct[lane][128] = (_Float16)(coords[r * 3 + 0] - coords[c * 3 + 0]);
            ct[lane][129] = (_Float16)(coords[r * 3 + 1] - coords[c * 3 + 1]);
            ct[lane][130] = (_Float16)(coords[r * 3 + 2] - coords[c * 3 + 2]);
        }
        LGKM0();

        f32x4 acc[2][8];
#pragma unroll
        for (int rt = 0; rt < 2; ++rt)
#pragma unroll
            for (int t = 0; t < 8; ++t) acc[rt][t] = (f32x4){0.f, 0.f, 0.f, 0.f};
#pragma unroll
        for (int ks = 0; ks < 5; ++ks) {
            f16x8 a0 = *(const f16x8*)&ct[lc][ks * 32 + lg * 8];
            f16x8 a1 = *(const f16x8*)&ct[16 + lc][ks * 32 + lg * 8];
#pragma unroll
            for (int t = 0; t < 8; ++t) {
                f16x8 b = *(const f16x8*)&w1T[(size_t)(t * 16 + lc) * 168 + ks * 32 + lg * 8];
                acc[0][t] = MFMA16(a0, b, acc[0][t]);
                acc[1][t] = MFMA16(a1, b, acc[1][t]);
            }
        }
        // silu -> back into cin tile (cols 0..127), wave-private so no barrier
#pragma unroll
        for (int t = 0; t < 8; ++t) {
            int colc = t * 16 + lc;
            float bias = b1[colc];
#pragma unroll
            for (int rt = 0; rt < 2; ++rt)
#pragma unroll
                for (int j = 0; j < 4; ++j)
                    ct[rt * 16 + lg * 4 + j][colc] = (_Float16)siluf_(acc[rt][t][j] + bias);
        }
        LGKM0();

        f32x4 acc2[2][4];
#pragma unroll
        for (int rt = 0; rt < 2; ++rt)
#pragma unroll
            for (int t = 0; t < 4; ++t) acc2[rt][t] = (f32x4){0.f, 0.f, 0.f, 0.f};
#pragma unroll
        for (int ks = 0; ks < 4; ++ks) {
            f16x8 a0 = *(const f16x8*)&ct[lc][ks * 32 + lg * 8];
            f16x8 a1 = *(const f16x8*)&ct[16 + lc][ks * 32 + lg * 8];
#pragma unroll
            for (int t = 0; t < 4; ++t) {
                f16x8 b = *(const f16x8*)&w2T[(size_t)(t * 16 + lc) * 136 + ks * 32 + lg * 8];
                acc2[0][t] = MFMA16(a0, b, acc2[0][t]);
                acc2[1][t] = MFMA16(a1, b, acc2[1][t]);
            }
        }
        int rr[8];
#pragma unroll
        for (int rt = 0; rt < 2; ++rt)
#pragma unroll
            for (int j = 0; j < 4; ++j) rr[rt * 4 + j] = row[e0 + rt * 16 + lg * 4 + j];
#pragma unroll
        for (int t = 0; t < 4; ++t) {
            int colc = t * 16 + lc;
            float bias = b2[colc];
#pragma unroll
            for (int rt = 0; rt < 2; ++rt)
#pragma unroll
                for (int j = 0; j < 4; ++j)
                    atomicAdd(&agg[(size_t)rr[rt * 4 + j] * 64 + colc],
                              siluf_(acc2[rt][t][j] + bias));
        }
    }
}

// ---- node kernel: GEMM1 ([h|agg] 128->128) + silu + GEMM2 (128->64) + residual + LN
__global__ __launch_bounds__(256)
void k_node_mfma(float* __restrict__ h32, _Float16* __restrict__ h16,
                 const float* __restrict__ agg,
                 const _Float16* __restrict__ w1T, const float* __restrict__ b1,
                 const _Float16* __restrict__ w2T, const float* __restrict__ b2) {
    __shared__ _Float16 cinL[4][32][136];
    int w = threadIdx.x >> 6, lane = threadIdx.x & 63;
    int lc = lane & 15, lg = lane >> 4;
    _Float16(*ct)[136] = cinL[w];
    int wid = blockIdx.x * 4 + w, nw = gridDim.x * 4;

    for (int tile = wid; tile < NN / 32; tile += nw) {
        int n0 = tile * 32;
        {
            int i = lane >> 1, part = lane & 1;
            int n = n0 + i;
            const f16x8* ph = (const f16x8*)(h16 + (size_t)n * 64 + part * 32);
            f16x8 h0 = ph[0], h1 = ph[1], h2 = ph[2], h3 = ph[3];
            f16x8* dh = (f16x8*)&ct[i][part * 32];
            dh[0] = h0; dh[1] = h1; dh[2] = h2; dh[3] = h3;
            const f32x4* pa = (const f32x4*)(agg + (size_t)n * 64 + part * 32);
            f16x8* da = (f16x8*)&ct[i][64 + part * 32];
#pragma unroll
            for (int v2 = 0; v2 < 4; ++v2) {
                f32x4 xx = pa[2 * v2], yy = pa[2 * v2 + 1];
                f16x8 o;
                o[0] = (_Float16)xx[0]; o[1] = (_Float16)xx[1];
                o[2] = (_Float16)xx[2]; o[3] = (_Float16)xx[3];
                o[4] = (_Float16)yy[0]; o[5] = (_Float16)yy[1];
                o[6] = (_Float16)yy[2]; o[7] = (_Float16)yy[3];
                da[v2] = o;
            }
        }
        LGKM0();

        f32x4 acc[2][8];
#pragma unroll
        for (int rt = 0; rt < 2; ++rt)
#pragma unroll
            for (int t = 0; t < 8; ++t) acc[rt][t] = (f32x4){0.f, 0.f, 0.f, 0.f};
#pragma unroll
        for (int ks = 0; ks < 4; ++ks) {
            f16x8 a0 = *(const f16x8*)&ct[lc][ks * 32 + lg * 8];
            f16x8 a1 = *(const f16x8*)&ct[16 + lc][ks * 32 + lg * 8];
#pragma unroll
            for (int t = 0; t < 8; ++t) {
                f16x8 b = *(const f16x8*)&w1T[(size_t)(t * 16 + lc) * 136 + ks * 32 + lg * 8];
                acc[0][t] = MFMA16(a0, b, acc[0][t]);
                acc[1][t] = MFMA16(a1, b, acc[1][t]);
            }
        }
#pragma unroll
        for (int t = 0; t < 8; ++t) {
            int colc = t * 16 + lc;
            float bias = b1[colc];
#pragma unroll
            for (int rt = 0; rt < 2; ++rt)
#pragma unroll
                for (int j = 0; j < 4; ++j)
                    ct[rt * 16 + lg * 4 + j][colc] = (_Float16)siluf_(acc[rt][t][j] + bias);
        }
        LGKM0();

        f32x4 acc2[2][4];
#pragma unroll
        for (int rt = 0; rt < 2; ++rt)
#pragma unroll
            for (int t = 0; t < 4; ++t) acc2[rt][t] = (f32x4){0.f, 0.f, 0.f, 0.f};
#pragma unroll
        for (int ks = 0; ks < 4; ++ks) {
            f16x8 a0 = *(const f16x8*)&ct[lc][ks * 32 + lg * 8];
            f16x8 a1 = *(const f16x8*)&ct[16 + lc][ks * 32 + lg * 8];
#pragma unroll
            for (int t = 0; t < 4; ++t) {
                f16x8 b = *(const f16x8*)&w2T[(size_t)(t * 16 + lc) * 136 + ks * 32 + lg * 8];
                acc2[0][t] = MFMA16(a0, b, acc2[0][t]);
                acc2[1][t] = MFMA16(a1, b, acc2[1][t]);
            }
        }
        // residual + LN over 64 cols (each lane holds 4 cols x 8 rows)
        float vv[2][4][4], sums[8], sqs[8];
#pragma unroll
        for (int q = 0; q < 8; ++q) { sums[q] = 0.f; sqs[q] = 0.f; }
#pragma unroll
        for (int rt = 0; rt < 2; ++rt)
#pragma unroll
            for (int t = 0; t < 4; ++t) {
                int colc = t * 16 + lc;
                float bias = b2[colc];
#pragma unroll
                for (int j = 0; j < 4; ++j) {
                    int rloc = rt * 16 + lg * 4 + j;
                    float val = h32[(size_t)(n0 + rloc) * 64 + colc] + acc2[rt][t][j] + bias;
                    vv[rt][t][j] = val;
                    sums[rt * 4 + j] += val;
                    sqs[rt * 4 + j] += val * val;
                }
            }
#pragma unroll
        for (int m = 1; m < 16; m <<= 1)
#pragma unroll
            for (int q = 0; q < 8; ++q) {
                sums[q] += __shfl_xor(sums[q], m);
                sqs[q] += __shfl_xor(sqs[q], m);
            }
#pragma unroll
        for (int rt = 0; rt < 2; ++rt)
#pragma unroll
            for (int j = 0; j < 4; ++j) {
                int q = rt * 4 + j;
                float mu = sums[q] * (1.0f / 64.0f);
                float var = sqs[q] * (1.0f / 64.0f) - mu * mu;
                float rs = rsqrtf(var + 1e-5f);
#pragma unroll
                for (int t = 0; t < 4; ++t) {
                    int colc = t * 16 + lc;
                    int rloc = rt * 16 + lg * 4 + j;
                    float out = (vv[rt][t][j] - mu) * rs;
                    size_t idx = (size_t)(n0 + rloc) * 64 + colc;
                    h32[idx] = out;
                    h16[idx] = (_Float16)out;
                }
            }
    }
}

// Segmented pool: batch is SORTED -> accumulate per-lane partials over a contiguous
// node chunk, flush one atomicAdd per group transition (was: 6.4M contended atomics).
__global__ void k_pool_seg(const float* __restrict__ h, const int* __restrict__ batch,
                           float* __restrict__ pooled, float* __restrict__ cnt) {
    int lane = threadIdx.x & 63;
    int wid = blockIdx.x * (blockDim.x >> 6) + (threadIdx.x >> 6);
    int nwav = gridDim.x * (blockDim.x >> 6);
    int chunk = (NN + nwav - 1) / nwav;
    int s = wid * chunk;
    if (s >= NN) return;
    int e = min(NN, s + chunk);
    int g = batch[s];
    float acc = 0.0f, c = 0.0f;
    for (int n = s; n < e; ++n) {
        int b = batch[n];
        if (b != g) {
            atomicAdd(&pooled[g * 64 + lane], acc);
            if (lane == 0) atomicAdd(&cnt[g], c);
            acc = 0.0f; c = 0.0f; g = b;
        }
        acc += h[(size_t)n * 64 + lane];
        c += 1.0f;
    }
    atomicAdd(&pooled[g * 64 + lane], acc);
    if (lane == 0) atomicAdd(&cnt[g], c);
}

__global__ void k_final(const float* __restrict__ pooled, const float* __restrict__ cnt,
                        const float* __restrict__ ow, const float* __restrict__ ob,
                        float* __restrict__ out) {
    __shared__ float red[2];
    int g = blockIdx.x, o = threadIdx.x;  // 128 threads
    float c = fmaxf(cnt[g], 1.0f);
    float acc = ob[o];
#pragma unroll
    for (int j = 0; j < 64; ++j) {
        float pm = fmaxf(pooled[g * 64 + j] / c, 0.0f);
        acc = fmaf(pm, ow[j * 128 + o], acc);
    }
    float ss = acc * acc;
#pragma unroll
    for (int off = 32; off > 0; off >>= 1) ss += __shfl_xor(ss, off);
    if ((o & 63) == 0) red[o >> 6] = ss;
    __syncthreads();
    float nrm = sqrtf(red[0] + red[1]);
    out[g * 128 + o] = acc / fmaxf(nrm, 1e-12f);
}

extern "C" void kernel_launch(void* const* d_in, const int* in_sizes, int n_in,
                              void* d_out, int out_size, void* d_ws, size_t ws_size,
                              hipStream_t stream) {
    const float* x         = (const float*)d_in[0];
    const float* coords_in = (const float*)d_in[1];
    const float* in_w      = (const float*)d_in[2];
    const float* in_b      = (const float*)d_in[3];
    const float* coord_w1  = (const float*)d_in[4];
    const float* coord_b1  = (const float*)d_in[5];
    const float* coord_w2  = (const float*)d_in[6];
    const float* coord_b2  = (const float*)d_in[7];
    const float* ew_w      = (const float*)d_in[8];
    const float* ew_b      = (const float*)d_in[9];
    const float* cn_scale  = (const float*)d_in[10];
    const float* edge_w1   = (const float*)d_in[11];
    const float* edge_b1   = (const float*)d_in[12];
    const float* edge_w2   = (const float*)d_in[13];
    const float* edge_b2   = (const float*)d_in[14];
    const float* node_w1   = (const float*)d_in[15];
    const float* node_b1   = (const float*)d_in[16];
    const float* node_w2   = (const float*)d_in[17];
    const float* node_b2   = (const float*)d_in[18];
    const float* out_w     = (const float*)d_in[19];
    const float* out_b     = (const float*)d_in[20];
    const int* ei          = (const int*)d_in[21];
    const int* batch       = (const int*)d_in[22];
    const int* row = ei;
    const int* col = ei + NE;

    char* wp = (char*)d_ws;
    float* h32    = (float*)wp; wp += (size_t)NN * 64 * 4;
    float* agg    = (float*)wp; wp += (size_t)NN * 64 * 4;
    float* cA     = (float*)wp; wp += (size_t)NN * 3 * 4;
    float* cB     = (float*)wp; wp += (size_t)NN * 3 * 4;
    float* pooled = (float*)wp; wp += (size_t)NG * 64 * 4;
    float* cnt    = (float*)wp; wp += (size_t)NG * 4;
    _Float16* h16  = (_Float16*)wp; wp += (size_t)NN * 64 * 2;
    _Float16* cw1T = (_Float16*)wp; wp += (size_t)NL * 128 * 168 * 2;
    _Float16* ew1T = (_Float16*)wp; wp += (size_t)NL * 128 * 168 * 2;
    _Float16* ew2T = (_Float16*)wp; wp += (size_t)NL * 64 * 136 * 2;
    _Float16* nw1T = (_Float16*)wp; wp += (size_t)NL * 128 * 136 * 2;
    _Float16* nw2T = (_Float16*)wp; wp += (size_t)NL * 64 * 136 * 2;

    k_prep_all<<<(NL * SEGTOT + 255) / 256, 256, 0, stream>>>(
        coord_w1, edge_w1, edge_w2, node_w1, node_w2, cw1T, ew1T, ew2T, nw1T, nw2T);
    k_init_h<<<(NN * 64 + 255) / 256, 256, 0, stream>>>(x, in_w, in_b, h32, h16);

    const float* cur = coords_in;
    float* nxt = cA;
    for (int l = 0; l < NL; ++l) {
        hipMemcpyAsync(nxt, cur, (size_t)NN * 3 * sizeof(float), hipMemcpyDeviceToDevice, stream);
        k_coord_mfma<<<2048, 256, 0, stream>>>(h16, cur, nxt, row, col,
            cw1T + (size_t)l * 128 * 168, coord_b1 + l * 128,
            coord_w2 + (size_t)l * 128 * 3, coord_b2 + l * 3,
            ew_w + l * 3, ew_b + l, cn_scale + l);
        hipMemsetAsync(agg, 0, (size_t)NN * 64 * sizeof(float), stream);
        k_edge_mfma<<<2048, 256, 0, stream>>>(h16, nxt, agg, row, col,
            ew1T + (size_t)l * 128 * 168, edge_b1 + l * 128,
            ew2T + (size_t)l * 64 * 136, edge_b2 + l * 64);
        k_node_mfma<<<782, 256, 0, stream>>>(h32, h16, agg,
            nw1T + (size_t)l * 128 * 136, node_b1 + l * 128,
            nw2T + (size_t)l * 64 * 136, node_b2 + l * 64);
        cur = nxt;
        nxt = (nxt == cA) ? cB : cA;
    }
    hipMemsetAsync(pooled, 0, (size_t)(NG * 64 + NG) * sizeof(float), stream);
    k_pool_seg<<<512, 256, 0, stream>>>(h32, batch, pooled, cnt);
    k_final<<<NG, 128, 0, stream>>>(pooled, cnt, out_w, out_b, (float*)d_out);
}

// Round 4
// 2517.803 us; speedup vs baseline: 30.8856x; 1.2078x over previous
//
#include <hip/hip_runtime.h>
#include <math.h>

#define NN 100000
#define NE 1000000
#define NG 64
#define NL 4

typedef __attribute__((ext_vector_type(8))) _Float16 f16x8;
typedef __attribute__((ext_vector_type(4))) float f32x4;

#define MFMA16(a, b, c) __builtin_amdgcn_mfma_f32_16x16x32_f16(a, b, c, 0, 0, 0)
#define LGKM0() asm volatile("s_waitcnt lgkmcnt(0)" ::: "memory")

#define LOG2E 1.44269504088896340f
// fast sigmoid/silu: v_exp_f32 + v_rcp_f32 (4 VALU ops vs ~10 for libm expf)
__device__ __forceinline__ float fsig_(float x) {
    return __builtin_amdgcn_rcpf(1.0f + __builtin_amdgcn_exp2f(-LOG2E * x));
}
__device__ __forceinline__ float fsilu_(float x) { return x * fsig_(x); }

__global__ void k_init_h(const float* __restrict__ x, const float* __restrict__ in_w,
                         const float* __restrict__ in_b, float* __restrict__ h32,
                         _Float16* __restrict__ h16) {
    int idx = blockIdx.x * blockDim.x + threadIdx.x;
    if (idx >= NN * 64) return;
    int n = idx >> 6, j = idx & 63;
    float v = fmaf(x[n], in_w[j], in_b[j]);
    h32[idx] = v;
    h16[idx] = (_Float16)v;
}

// One fused prep: transpose + fp16 + zero-pad all weight families x 4 layers.
#define SEG0 21504  // 128*168 cw1T (K=131,O=128,SD=168)
#define SEG1 21504  // ew1T
#define SEG2 8704   // 64*136  ew2T (K=128,O=64, SD=136)
#define SEG3 17408  // 128*136 nw1T (K=128,O=128,SD=136)
#define SEG4 8704   // nw2T
#define SEG5 2176   // 16*136  cw2T (K=128,O=3 padded to 16, SD=136)
#define SEGTOT (SEG0 + SEG1 + SEG2 + SEG3 + SEG4 + SEG5)
__global__ void k_prep_all(const float* __restrict__ cw1, const float* __restrict__ ew1,
                           const float* __restrict__ ew2, const float* __restrict__ nw1,
                           const float* __restrict__ nw2, const float* __restrict__ cw2,
                           _Float16* __restrict__ cw1T, _Float16* __restrict__ ew1T,
                           _Float16* __restrict__ ew2T, _Float16* __restrict__ nw1T,
                           _Float16* __restrict__ nw2T, _Float16* __restrict__ cw2T) {
    int i = blockIdx.x * blockDim.x + threadIdx.x;
    if (i >= NL * SEGTOT) return;
    int l = i / SEGTOT, r = i - l * SEGTOT;
    const float* src; _Float16* dst; int K, O, SD, j;
    if (r < SEG0) { src = cw1 + (size_t)l * 131 * 128; dst = cw1T + (size_t)l * SEG0; K = 131; O = 128; SD = 168; j = r; }
    else if ((r -= SEG0) < SEG1) { src = ew1 + (size_t)l * 131 * 128; dst = ew1T + (size_t)l * SEG1; K = 131; O = 128; SD = 168; j = r; }
    else if ((r -= SEG1) < SEG2) { src = ew2 + (size_t)l * 128 * 64; dst = ew2T + (size_t)l * SEG2; K = 128; O = 64; SD = 136; j = r; }
    else if ((r -= SEG2) < SEG3) { src = nw1 + (size_t)l * 128 * 128; dst = nw1T + (size_t)l * SEG3; K = 128; O = 128; SD = 136; j = r; }
    else if ((r -= SEG3) < SEG4) { src = nw2 + (size_t)l * 128 * 64; dst = nw2T + (size_t)l * SEG4; K = 128; O = 64; SD = 136; j = r; }
    else {  // coord W2: [128][3] -> [16][136], cols>=3 zero
        r -= SEG4;
        const float* s2 = cw2 + (size_t)l * 128 * 3;
        int o = r / 136, k = r - o * 136;
        cw2T[(size_t)l * SEG5 + r] = (o < 3 && k < 128) ? (_Float16)s2[(size_t)k * 3 + o] : (_Float16)0.0f;
        return;
    }
    int o = j / SD, k = j - o * SD;
    dst[j] = (k < K) ? (_Float16)src[(size_t)k * O + o] : (_Float16)0.0f;
}

// ---- coord kernel: GEMM1 (K=131 pad 160) + silu->LDS + GEMM2 MFMA (128->16pad) + CoorsNorm/gate/atomic
__global__ __launch_bounds__(256)
void k_coord_mfma(const _Float16* __restrict__ h16,
                  const float* __restrict__ ccur, float* __restrict__ cnext,
                  const int* __restrict__ row, const int* __restrict__ col,
                  const _Float16* __restrict__ w1T, const float* __restrict__ b1,
                  const _Float16* __restrict__ w2T, const float* __restrict__ b2,
                  const float* __restrict__ eww, const float* __restrict__ ewb,
                  const float* __restrict__ cns) {
    __shared__ _Float16 cinL[4][32][168];
    __shared__ float gateL[4][32];
    {
        _Float16* z = &cinL[0][0][0];
        for (int i = threadIdx.x; i < 4 * 32 * 168; i += 256) z[i] = (_Float16)0.0f;
    }
    __syncthreads();
    int w = threadIdx.x >> 6, lane = threadIdx.x & 63;
    int lc = lane & 15, lg = lane >> 4;
    float e0w = eww[0], e1w = eww[1], e2w = eww[2], ebw = ewb[0], sc = cns[0];
    _Float16(*ct)[168] = cinL[w];
    float* gt = gateL[w];
    int wid = blockIdx.x * 4 + w, nw = gridDim.x * 4;
    float bb2 = (lc < 3) ? b2[lc] : 0.0f;

    for (int tile = wid; tile < NE / 32; tile += nw) {
        int e0 = tile * 32;
        {   // stage h[row] -> cols 0..63, h[col] -> cols 64..127 (2 lanes/edge)
            int e = e0 + (lane >> 1), part = lane & 1;
            int r = row[e], c = col[e];
            const f16x8* pr = (const f16x8*)(h16 + (size_t)r * 64 + part * 32);
            const f16x8* pc = (const f16x8*)(h16 + (size_t)c * 64 + part * 32);
            f16x8 r0 = pr[0], r1 = pr[1], r2 = pr[2], r3 = pr[3];
            f16x8 c0 = pc[0], c1 = pc[1], c2 = pc[2], c3 = pc[3];
            f16x8* dr = (f16x8*)&ct[lane >> 1][part * 32];
            dr[0] = r0; dr[1] = r1; dr[2] = r2; dr[3] = r3;
            f16x8* dc = (f16x8*)&ct[lane >> 1][64 + part * 32];
            dc[0] = c0; dc[1] = c1; dc[2] = c2; dc[3] = c3;
        }
        if (lane < 32) {  // rel (OLD coords) -> cols 128..130, gate -> gt
            int e = e0 + lane;
            int r = row[e], c = col[e];
            float rx = ccur[r * 3 + 0] - ccur[c * 3 + 0];
            float ry = ccur[r * 3 + 1] - ccur[c * 3 + 1];
            float rz = ccur[r * 3 + 2] - ccur[c * 3 + 2];
            ct[lane][128] = (_Float16)rx;
            ct[lane][129] = (_Float16)ry;
            ct[lane][130] = (_Float16)rz;
            gt[lane] = fsig_(fmaf(rx, e0w, fmaf(ry, e1w, fmaf(rz, e2w, ebw))));
        }
        LGKM0();

        f32x4 acc[2][8];
#pragma unroll
        for (int rt = 0; rt < 2; ++rt)
#pragma unroll
            for (int t = 0; t < 8; ++t) acc[rt][t] = (f32x4){0.f, 0.f, 0.f, 0.f};
#pragma unroll
        for (int ks = 0; ks < 5; ++ks) {
            f16x8 a0 = *(const f16x8*)&ct[lc][ks * 32 + lg * 8];
            f16x8 a1 = *(const f16x8*)&ct[16 + lc][ks * 32 + lg * 8];
#pragma unroll
            for (int t = 0; t < 8; ++t) {
                f16x8 b = *(const f16x8*)&w1T[(size_t)(t * 16 + lc) * 168 + ks * 32 + lg * 8];
                acc[0][t] = MFMA16(a0, b, acc[0][t]);
                acc[1][t] = MFMA16(a1, b, acc[1][t]);
            }
        }
        // silu -> back into tile cols 0..127 (wave-private, no barrier)
#pragma unroll
        for (int t = 0; t < 8; ++t) {
            int colc = t * 16 + lc;
            float bias = b1[colc];
#pragma unroll
            for (int rt = 0; rt < 2; ++rt)
#pragma unroll
                for (int j = 0; j < 4; ++j)
                    ct[rt * 16 + lg * 4 + j][colc] = (_Float16)fsilu_(acc[rt][t][j] + bias);
        }
        LGKM0();

        // GEMM2 via MFMA: [32,128] @ [128,16pad(3)]
        f32x4 acc2[2];
        acc2[0] = (f32x4){0.f, 0.f, 0.f, 0.f};
        acc2[1] = (f32x4){0.f, 0.f, 0.f, 0.f};
#pragma unroll
        for (int ks = 0; ks < 4; ++ks) {
            f16x8 a0 = *(const f16x8*)&ct[lc][ks * 32 + lg * 8];
            f16x8 a1 = *(const f16x8*)&ct[16 + lc][ks * 32 + lg * 8];
            f16x8 b = *(const f16x8*)&w2T[(size_t)lc * 136 + ks * 32 + lg * 8];
            acc2[0] = MFMA16(a0, b, acc2[0]);
            acc2[1] = MFMA16(a1, b, acc2[1]);
        }
        // epilogue: lane(lc<3) holds delta[row][lc]; norm over lc via 2 shuffles
#pragma unroll
        for (int rt = 0; rt < 2; ++rt)
#pragma unroll
            for (int j = 0; j < 4; ++j) {
                float d = acc2[rt][j] + bb2;
                float ss = d * d;
                ss += __shfl_xor(ss, 1);
                ss += __shfl_xor(ss, 2);
                int rloc = rt * 16 + lg * 4 + j;
                float nrm = fmaxf(__builtin_amdgcn_sqrtf(ss), 1e-8f);
                float m = sc * __builtin_amdgcn_rcpf(nrm) * gt[rloc];
                if (lc < 3)
                    atomicAdd(&cnext[(size_t)row[e0 + rloc] * 3 + lc], d * m);
            }
    }
}

// ---- edge kernel: GEMM1 (131->128) + silu + GEMM2 (128->64) + silu + scatter-add
__global__ __launch_bounds__(256)
void k_edge_mfma(const _Float16* __restrict__ h16,
                 const float* __restrict__ coords, float* __restrict__ agg,
                 const int* __restrict__ row, const int* __restrict__ col,
                 const _Float16* __restrict__ w1T, const float* __restrict__ b1,
                 const _Float16* __restrict__ w2T, const float* __restrict__ b2) {
    __shared__ _Float16 cinL[4][32][168];
    {
        _Float16* z = &cinL[0][0][0];
        for (int i = threadIdx.x; i < 4 * 32 * 168; i += 256) z[i] = (_Float16)0.0f;
    }
    __syncthreads();
    int w = threadIdx.x >> 6, lane = threadIdx.x & 63;
    int lc = lane & 15, lg = lane >> 4;
    _Float16(*ct)[168] = cinL[w];
    int wid = blockIdx.x * 4 + w, nw = gridDim.x * 4;

    for (int tile = wid; tile < NE / 32; tile += nw) {
        int e0 = tile * 32;
        {
            int e = e0 + (lane >> 1), part = lane & 1;
            int r = row[e], c = col[e];
            const f16x8* pr = (const f16x8*)(h16 + (size_t)r * 64 + part * 32);
            const f16x8* pc = (const f16x8*)(h16 + (size_t)c * 64 + part * 32);
            f16x8 r0 = pr[0], r1 = pr[1], r2 = pr[2], r3 = pr[3];
            f16x8 c0 = pc[0], c1 = pc[1], c2 = pc[2], c3 = pc[3];
            f16x8* dr = (f16x8*)&ct[lane >> 1][part * 32];
            dr[0] = r0; dr[1] = r1; dr[2] = r2; dr[3] = r3;
            f16x8* dc = (f16x8*)&ct[lane >> 1][64 + part * 32];
            dc[0] = c0; dc[1] = c1; dc[2] = c2; dc[3] = c3;
        }
        if (lane < 32) {  // rel (NEW coords)
            int e = e0 + lane;
            int r = row[e], c = col[e];
            ct[lane][128] = (_Float16)(coords[r * 3 + 0] - coords[c * 3 + 0]);
            ct[lane][129] = (_Float16)(coords[r * 3 + 1] - coords[c * 3 + 1]);
            ct[lane][130] = (_Float16)(coords[r * 3 + 2] - coords[c * 3 + 2]);
        }
        LGKM0();

        f32x4 acc[2][8];
#pragma unroll
        for (int rt = 0; rt < 2; ++rt)
#pragma unroll
            for (int t = 0; t < 8; ++t) acc[rt][t] = (f32x4){0.f, 0.f, 0.f, 0.f};
#pragma unroll
        for (int ks = 0; ks < 5; ++ks) {
            f16x8 a0 = *(const f16x8*)&ct[lc][ks * 32 + lg * 8];
            f16x8 a1 = *(const f16x8*)&ct[16 + lc][ks * 32 + lg * 8];
#pragma unroll
            for (int t = 0; t < 8; ++t) {
                f16x8 b = *(const f16x8*)&w1T[(size_t)(t * 16 + lc) * 168 + ks * 32 + lg * 8];
                acc[0][t] = MFMA16(a0, b, acc[0][t]);
                acc[1][t] = MFMA16(a1, b, acc[1][t]);
            }
        }
#pragma unroll
        for (int t = 0; t < 8; ++t) {
            int colc = t * 16 + lc;
            float bias = b1[colc];
#pragma unroll
            for (int rt = 0; rt < 2; ++rt)
#pragma unroll
                for (int j = 0; j < 4; ++j)
                    ct[rt * 16 + lg * 4 + j][colc] = (_Float16)fsilu_(acc[rt][t][j] + bias);
        }
        LGKM0();

        f32x4 acc2[2][4];
#pragma unroll
        for (int rt = 0; rt < 2; ++rt)
#pragma unroll
            for (int t = 0; t < 4; ++t) acc2[rt][t] = (f32x4){0.f, 0.f, 0.f, 0.f};
#pragma unroll
        for (int ks = 0; ks < 4; ++ks) {
            f16x8 a0 = *(const f16x8*)&ct[lc][ks * 32 + lg * 8];
            f16x8 a1 = *(const f16x8*)&ct[16 + lc][ks * 32 + lg * 8];
#pragma unroll
            for (int t = 0; t < 4; ++t) {
                f16x8 b = *(const f16x8*)&w2T[(size_t)(t * 16 + lc) * 136 + ks * 32 + lg * 8];
                acc2[0][t] = MFMA16(a0, b, acc2[0][t]);
                acc2[1][t] = MFMA16(a1, b, acc2[1][t]);
            }
        }
        int rr[8];
#pragma unroll
        for (int rt = 0; rt < 2; ++rt)
#pragma unroll
            for (int j = 0; j < 4; ++j) rr[rt * 4 + j] = row[e0 + rt * 16 + lg * 4 + j];
#pragma unroll
        for (int t = 0; t < 4; ++t) {
            int colc = t * 16 + lc;
            float bias = b2[colc];
#pragma unroll
            for (int rt = 0; rt < 2; ++rt)
#pragma unroll
                for (int j = 0; j < 4; ++j)
                    atomicAdd(&agg[(size_t)rr[rt * 4 + j] * 64 + colc],
                              fsilu_(acc2[rt][t][j] + bias));
        }
    }
}

// ---- node kernel: GEMM1 ([h|agg] 128->128) + silu + GEMM2 (128->64) + residual + LN
__global__ __launch_bounds__(256)
void k_node_mfma(float* __restrict__ h32, _Float16* __restrict__ h16,
                 const float* __restrict__ agg,
                 const _Float16* __restrict__ w1T, const float* __restrict__ b1,
                 const _Float16* __restrict__ w2T, const float* __restrict__ b2) {
    __shared__ _Float16 cinL[4][32][136];
    int w = threadIdx.x >> 6, lane = threadIdx.x & 63;
    int lc = lane & 15, lg = lane >> 4;
    _Float16(*ct)[136] = cinL[w];
    int wid = blockIdx.x * 4 + w, nw = gridDim.x * 4;

    for (int tile = wid; tile < NN / 32; tile += nw) {
        int n0 = tile * 32;
        {
            int i = lane >> 1, part = lane & 1;
            int n = n0 + i;
            const f16x8* ph = (const f16x8*)(h16 + (size_t)n * 64 + part * 32);
            f16x8 h0 = ph[0], h1 = ph[1], h2 = ph[2], h3 = ph[3];
            f16x8* dh = (f16x8*)&ct[i][part * 32];
            dh[0] = h0; dh[1] = h1; dh[2] = h2; dh[3] = h3;
            const f32x4* pa = (const f32x4*)(agg + (size_t)n * 64 + part * 32);
            f16x8* da = (f16x8*)&ct[i][64 + part * 32];
#pragma unroll
            for (int v2 = 0; v2 < 4; ++v2) {
                f32x4 xx = pa[2 * v2], yy = pa[2 * v2 + 1];
                f16x8 o;
                o[0] = (_Float16)xx[0]; o[1] = (_Float16)xx[1];
                o[2] = (_Float16)xx[2]; o[3] = (_Float16)xx[3];
                o[4] = (_Float16)yy[0]; o[5] = (_Float16)yy[1];
                o[6] = (_Float16)yy[2]; o[7] = (_Float16)yy[3];
                da[v2] = o;
            }
        }
        LGKM0();

        f32x4 acc[2][8];
#pragma unroll
        for (int rt = 0; rt < 2; ++rt)
#pragma unroll
            for (int t = 0; t < 8; ++t) acc[rt][t] = (f32x4){0.f, 0.f, 0.f, 0.f};
#pragma unroll
        for (int ks = 0; ks < 4; ++ks) {
            f16x8 a0 = *(const f16x8*)&ct[lc][ks * 32 + lg * 8];
            f16x8 a1 = *(const f16x8*)&ct[16 + lc][ks * 32 + lg * 8];
#pragma unroll
            for (int t = 0; t < 8; ++t) {
                f16x8 b = *(const f16x8*)&w1T[(size_t)(t * 16 + lc) * 136 + ks * 32 + lg * 8];
                acc[0][t] = MFMA16(a0, b, acc[0][t]);
                acc[1][t] = MFMA16(a1, b, acc[1][t]);
            }
        }
#pragma unroll
        for (int t = 0; t < 8; ++t) {
            int colc = t * 16 + lc;
            float bias = b1[colc];
#pragma unroll
            for (int rt = 0; rt < 2; ++rt)
#pragma unroll
                for (int j = 0; j < 4; ++j)
                    ct[rt * 16 + lg * 4 + j][colc] = (_Float16)fsilu_(acc[rt][t][j] + bias);
        }
        LGKM0();

        f32x4 acc2[2][4];
#pragma unroll
        for (int rt = 0; rt < 2; ++rt)
#pragma unroll
            for (int t = 0; t < 4; ++t) acc2[rt][t] = (f32x4){0.f, 0.f, 0.f, 0.f};
#pragma unroll
        for (int ks = 0; ks < 4; ++ks) {
            f16x8 a0 = *(const f16x8*)&ct[lc][ks * 32 + lg * 8];
            f16x8 a1 = *(const f16x8*)&ct[16 + lc][ks * 32 + lg * 8];
#pragma unroll
            for (int t = 0; t < 4; ++t) {
                f16x8 b = *(const f16x8*)&w2T[(size_t)(t * 16 + lc) * 136 + ks * 32 + lg * 8];
                acc2[0][t] = MFMA16(a0, b, acc2[0][t]);
                acc2[1][t] = MFMA16(a1, b, acc2[1][t]);
            }
        }
        float vv[2][4][4], sums[8], sqs[8];
#pragma unroll
        for (int q = 0; q < 8; ++q) { sums[q] = 0.f; sqs[q] = 0.f; }
#pragma unroll
        for (int rt = 0; rt < 2; ++rt)
#pragma unroll
            for (int t = 0; t < 4; ++t) {
                int colc = t * 16 + lc;
                float bias = b2[colc];
#pragma unroll
                for (int j = 0; j < 4; ++j) {
                    int rloc = rt * 16 + lg * 4 + j;
                    float val = h32[(size_t)(n0 + rloc) * 64 + colc] + acc2[rt][t][j] + bias;
                    vv[rt][t][j] = val;
                    sums[rt * 4 + j] += val;
                    sqs[rt * 4 + j] += val * val;
                }
            }
#pragma unroll
        for (int m = 1; m < 16; m <<= 1)
#pragma unroll
            for (int q = 0; q < 8; ++q) {
                sums[q] += __shfl_xor(sums[q], m);
                sqs[q] += __shfl_xor(sqs[q], m);
            }
#pragma unroll
        for (int rt = 0; rt < 2; ++rt)
#pragma unroll
            for (int j = 0; j < 4; ++j) {
                int q = rt * 4 + j;
                float mu = sums[q] * (1.0f / 64.0f);
                float var = sqs[q] * (1.0f / 64.0f) - mu * mu;
                float rs = __builtin_amdgcn_rcpf(__builtin_amdgcn_sqrtf(var + 1e-5f));
#pragma unroll
                for (int t = 0; t < 4; ++t) {
                    int colc = t * 16 + lc;
                    int rloc = rt * 16 + lg * 4 + j;
                    float out = (vv[rt][t][j] - mu) * rs;
                    size_t idx = (size_t)(n0 + rloc) * 64 + colc;
                    h32[idx] = out;
                    h16[idx] = (_Float16)out;
                }
            }
    }
}

// Segmented pool over sorted batch ids.
__global__ void k_pool_seg(const float* __restrict__ h, const int* __restrict__ batch,
                           float* __restrict__ pooled, float* __restrict__ cnt) {
    int lane = threadIdx.x & 63;
    int wid = blockIdx.x * (blockDim.x >> 6) + (threadIdx.x >> 6);
    int nwav = gridDim.x * (blockDim.x >> 6);
    int chunk = (NN + nwav - 1) / nwav;
    int s = wid * chunk;
    if (s >= NN) return;
    int e = min(NN, s + chunk);
    int g = batch[s];
    float acc = 0.0f, c = 0.0f;
    for (int n = s; n < e; ++n) {
        int b = batch[n];
        if (b != g) {
            atomicAdd(&pooled[g * 64 + lane], acc);
            if (lane == 0) atomicAdd(&cnt[g], c);
            acc = 0.0f; c = 0.0f; g = b;
        }
        acc += h[(size_t)n * 64 + lane];
        c += 1.0f;
    }
    atomicAdd(&pooled[g * 64 + lane], acc);
    if (lane == 0) atomicAdd(&cnt[g], c);
}

__global__ void k_final(const float* __restrict__ pooled, const float* __restrict__ cnt,
                        const float* __restrict__ ow, const float* __restrict__ ob,
                        float* __restrict__ out) {
    __shared__ float red[2];
    int g = blockIdx.x, o = threadIdx.x;  // 128 threads
    float c = fmaxf(cnt[g], 1.0f);
    float acc = ob[o];
#pragma unroll
    for (int j = 0; j < 64; ++j) {
        float pm = fmaxf(pooled[g * 64 + j] / c, 0.0f);
        acc = fmaf(pm, ow[j * 128 + o], acc);
    }
    float ss = acc * acc;
#pragma unroll
    for (int off = 32; off > 0; off >>= 1) ss += __shfl_xor(ss, off);
    if ((o & 63) == 0) red[o >> 6] = ss;
    __syncthreads();
    float nrm = sqrtf(red[0] + red[1]);
    out[g * 128 + o] = acc / fmaxf(nrm, 1e-12f);
}

extern "C" void kernel_launch(void* const* d_in, const int* in_sizes, int n_in,
                              void* d_out, int out_size, void* d_ws, size_t ws_size,
                              hipStream_t stream) {
    const float* x         = (const float*)d_in[0];
    const float* coords_in = (const float*)d_in[1];
    const float* in_w      = (const float*)d_in[2];
    const float* in_b      = (const float*)d_in[3];
    const float* coord_w1  = (const float*)d_in[4];
    const float* coord_b1  = (const float*)d_in[5];
    const float* coord_w2  = (const float*)d_in[6];
    const float* coord_b2  = (const float*)d_in[7];
    const float* ew_w      = (const float*)d_in[8];
    const float* ew_b      = (const float*)d_in[9];
    const float* cn_scale  = (const float*)d_in[10];
    const float* edge_w1   = (const float*)d_in[11];
    const float* edge_b1   = (const float*)d_in[12];
    const float* edge_w2   = (const float*)d_in[13];
    const float* edge_b2   = (const float*)d_in[14];
    const float* node_w1   = (const float*)d_in[15];
    const float* node_b1   = (const float*)d_in[16];
    const float* node_w2   = (const float*)d_in[17];
    const float* node_b2   = (const float*)d_in[18];
    const float* out_w     = (const float*)d_in[19];
    const float* out_b     = (const float*)d_in[20];
    const int* ei          = (const int*)d_in[21];
    const int* batch       = (const int*)d_in[22];
    const int* row = ei;
    const int* col = ei + NE;

    char* wp = (char*)d_ws;
    float* h32    = (float*)wp; wp += (size_t)NN * 64 * 4;
    float* agg    = (float*)wp; wp += (size_t)NN * 64 * 4;
    float* cA     = (float*)wp; wp += (size_t)NN * 3 * 4;
    float* cB     = (float*)wp; wp += (size_t)NN * 3 * 4;
    float* pooled = (float*)wp; wp += (size_t)NG * 64 * 4;
    float* cnt    = (float*)wp; wp += (size_t)NG * 4;
    _Float16* h16  = (_Float16*)wp; wp += (size_t)NN * 64 * 2;
    _Float16* cw1T = (_Float16*)wp; wp += (size_t)NL * SEG0 * 2;
    _Float16* ew1T = (_Float16*)wp; wp += (size_t)NL * SEG1 * 2;
    _Float16* ew2T = (_Float16*)wp; wp += (size_t)NL * SEG2 * 2;
    _Float16* nw1T = (_Float16*)wp; wp += (size_t)NL * SEG3 * 2;
    _Float16* nw2T = (_Float16*)wp; wp += (size_t)NL * SEG4 * 2;
    _Float16* cw2T = (_Float16*)wp; wp += (size_t)NL * SEG5 * 2;

    k_prep_all<<<(NL * SEGTOT + 255) / 256, 256, 0, stream>>>(
        coord_w1, edge_w1, edge_w2, node_w1, node_w2, coord_w2,
        cw1T, ew1T, ew2T, nw1T, nw2T, cw2T);
    k_init_h<<<(NN * 64 + 255) / 256, 256, 0, stream>>>(x, in_w, in_b, h32, h16);

    const float* cur = coords_in;
    float* nxt = cA;
    for (int l = 0; l < NL; ++l) {
        hipMemcpyAsync(nxt, cur, (size_t)NN * 3 * sizeof(float), hipMemcpyDeviceToDevice, stream);
        k_coord_mfma<<<2048, 256, 0, stream>>>(h16, cur, nxt, row, col,
            cw1T + (size_t)l * SEG0, coord_b1 + l * 128,
            cw2T + (size_t)l * SEG5, coord_b2 + l * 3,
            ew_w + l * 3, ew_b + l, cn_scale + l);
        hipMemsetAsync(agg, 0, (size_t)NN * 64 * sizeof(float), stream);
        k_edge_mfma<<<2048, 256, 0, stream>>>(h16, nxt, agg, row, col,
            ew1T + (size_t)l * SEG1, edge_b1 + l * 128,
            ew2T + (size_t)l * SEG2, edge_b2 + l * 64);
        k_node_mfma<<<782, 256, 0, stream>>>(h32, h16, agg,
            nw1T + (size_t)l * SEG3, node_b1 + l * 128,
            nw2T + (size_t)l * SEG4, node_b2 + l * 64);
        cur = nxt;
        nxt = (nxt == cA) ? cB : cA;
    }
    hipMemsetAsync(pooled, 0, (size_t)(NG * 64 + NG) * sizeof(float), stream);
    k_pool_seg<<<512, 256, 0, stream>>>(h32, batch, pooled, cnt);
    k_final<<<NG, 128, 0, stream>>>(pooled, cnt, out_w, out_b, (float*)d_out);
}

// Round 5
// 1738.573 us; speedup vs baseline: 44.7286x; 1.4482x over previous
//
#include <hip/hip_runtime.h>
#include <math.h>

#define NN 100000
#define NE 1000000
#define NG 64
#define NL 4
#define NT_E (NE / 32)
#define NT_N (NN / 32)

typedef __attribute__((ext_vector_type(8))) _Float16 f16x8;
typedef __attribute__((ext_vector_type(4))) float f32x4;

#define MFMA16(a, b, c) __builtin_amdgcn_mfma_f32_16x16x32_f16(a, b, c, 0, 0, 0)
#define LOG2E 1.44269504088896340f
__device__ __forceinline__ float fsig_(float x) {
    return __builtin_amdgcn_rcpf(1.0f + __builtin_amdgcn_exp2f(-LOG2E * x));
}
__device__ __forceinline__ float fsilu_(float x) { return x * fsig_(x); }

__global__ void k_init_h(const float* __restrict__ x, const float* __restrict__ in_w,
                         const float* __restrict__ in_b, float* __restrict__ h32,
                         _Float16* __restrict__ h16) {
    int idx = blockIdx.x * blockDim.x + threadIdx.x;
    if (idx >= NN * 64) return;
    int n = idx >> 6, j = idx & 63;
    float v = fmaf(x[n], in_w[j], in_b[j]);
    h32[idx] = v;
    h16[idx] = (_Float16)v;
}

// transpose + fp16 + zero-pad all weight families x 4 layers
#define SEG0 21504  // 128*168 cw1T
#define SEG1 21504  // ew1T
#define SEG2 8704   // 64*136  ew2T
#define SEG3 17408  // 128*136 nw1T
#define SEG4 8704   // nw2T
#define SEG5 2176   // 16*136  cw2T (O=3 padded to 16)
#define SEGTOT (SEG0 + SEG1 + SEG2 + SEG3 + SEG4 + SEG5)
__global__ void k_prep_all(const float* __restrict__ cw1, const float* __restrict__ ew1,
                           const float* __restrict__ ew2, const float* __restrict__ nw1,
                           const float* __restrict__ nw2, const float* __restrict__ cw2,
                           _Float16* __restrict__ cw1T, _Float16* __restrict__ ew1T,
                           _Float16* __restrict__ ew2T, _Float16* __restrict__ nw1T,
                           _Float16* __restrict__ nw2T, _Float16* __restrict__ cw2T) {
    int i = blockIdx.x * blockDim.x + threadIdx.x;
    if (i >= NL * SEGTOT) return;
    int l = i / SEGTOT, r = i - l * SEGTOT;
    const float* src; _Float16* dst; int K, O, SD, j;
    if (r < SEG0) { src = cw1 + (size_t)l * 131 * 128; dst = cw1T + (size_t)l * SEG0; K = 131; O = 128; SD = 168; j = r; }
    else if ((r -= SEG0) < SEG1) { src = ew1 + (size_t)l * 131 * 128; dst = ew1T + (size_t)l * SEG1; K = 131; O = 128; SD = 168; j = r; }
    else if ((r -= SEG1) < SEG2) { src = ew2 + (size_t)l * 128 * 64; dst = ew2T + (size_t)l * SEG2; K = 128; O = 64; SD = 136; j = r; }
    else if ((r -= SEG2) < SEG3) { src = nw1 + (size_t)l * 128 * 128; dst = nw1T + (size_t)l * SEG3; K = 128; O = 128; SD = 136; j = r; }
    else if ((r -= SEG3) < SEG4) { src = nw2 + (size_t)l * 128 * 64; dst = nw2T + (size_t)l * SEG4; K = 128; O = 64; SD = 136; j = r; }
    else {
        r -= SEG4;
        const float* s2 = cw2 + (size_t)l * 128 * 3;
        int o = r / 136, k = r - o * 136;
        cw2T[(size_t)l * SEG5 + r] = (o < 3 && k < 128) ? (_Float16)s2[(size_t)k * 3 + o] : (_Float16)0.0f;
        return;
    }
    int o = j / SD, k = j - o * SD;
    dst[j] = (k < K) ? (_Float16)src[(size_t)k * O + o] : (_Float16)0.0f;
}

// ---- CSR build (once per launch) ----
__global__ void k_hist(const int* __restrict__ row, int* __restrict__ deg) {
    int e = blockIdx.x * blockDim.x + threadIdx.x;
    if (e < NE) atomicAdd(&deg[row[e]], 1);
}
__global__ void k_scan(const int* __restrict__ deg, int* __restrict__ rowptr) {
    __shared__ int ss[256];
    int t = threadIdx.x;
    const int CH = (NN + 255) / 256;
    int base = t * CH;
    int end = base + CH; if (end > NN) end = NN;
    int s = 0;
    for (int i = base; i < end; ++i) s += deg[i];
    ss[t] = s;
    __syncthreads();
    if (t == 0) {
        int run = 0;
        for (int i = 0; i < 256; ++i) { int v = ss[i]; ss[i] = run; run += v; }
    }
    __syncthreads();
    int run = ss[t];
    for (int i = base; i < end; ++i) { rowptr[i] = run; run += deg[i]; }
    if (t == 0) rowptr[NN] = NE;
}
__global__ void k_scatter(const int* __restrict__ row, int* __restrict__ pos,
                          int* __restrict__ eperm) {
    int e = blockIdx.x * blockDim.x + threadIdx.x;
    if (e < NE) { int p = atomicAdd(&pos[row[e]], 1); eperm[p] = e; }
}

// ---- coord: block-coop GEMM1 (reg weights) + ks-split GEMM2 + epilogue ----
__global__ __launch_bounds__(256)
void k_coord2(const _Float16* __restrict__ h16,
              const float* __restrict__ ccur, float* __restrict__ cnext,
              const int* __restrict__ row, const int* __restrict__ col,
              const _Float16* __restrict__ w1T, const float* __restrict__ b1,
              const _Float16* __restrict__ w2T, const float* __restrict__ b2,
              const float* __restrict__ eww, const float* __restrict__ ewb,
              const float* __restrict__ cns) {
    __shared__ __attribute__((aligned(16))) _Float16 cin[32][168];
    __shared__ __attribute__((aligned(16))) _Float16 h1[32][136];
    __shared__ __attribute__((aligned(16))) float pbuf[4][32][17];
    __shared__ float gate[32];
    for (int i = threadIdx.x; i < 32 * 168; i += 256) (&cin[0][0])[i] = (_Float16)0.0f;
    int tid = threadIdx.x;
    int w = tid >> 6, lane = tid & 63, lc = lane & 15, lg = lane >> 4;
    float e0w = eww[0], e1w = eww[1], e2w = eww[2], ebw = ewb[0], sc = cns[0];
    float b20 = b2[0], b21 = b2[1], b22 = b2[2];
    f16x8 bw1[2][5];
#pragma unroll
    for (int ti = 0; ti < 2; ++ti)
#pragma unroll
        for (int ks = 0; ks < 5; ++ks)
            bw1[ti][ks] = *(const f16x8*)&w1T[(size_t)((2 * w + ti) * 16 + lc) * 168 + ks * 32 + lg * 8];
    f16x8 bw2 = *(const f16x8*)&w2T[(size_t)lc * 136 + w * 32 + lg * 8];
    float bias10 = b1[(2 * w) * 16 + lc], bias11 = b1[(2 * w + 1) * 16 + lc];
    __syncthreads();

    for (int tile = blockIdx.x; tile < NT_E; tile += gridDim.x) {
        int e0 = tile * 32;
        {
            int el = tid >> 3, part = tid & 7;
            int r = row[e0 + el], c = col[e0 + el];
            *(f16x8*)&cin[el][part * 8] = *(const f16x8*)&h16[(size_t)r * 64 + part * 8];
            *(f16x8*)&cin[el][64 + part * 8] = *(const f16x8*)&h16[(size_t)c * 64 + part * 8];
        }
        if (tid < 32) {
            int r = row[e0 + tid], c = col[e0 + tid];
            float rx = ccur[r * 3 + 0] - ccur[c * 3 + 0];
            float ry = ccur[r * 3 + 1] - ccur[c * 3 + 1];
            float rz = ccur[r * 3 + 2] - ccur[c * 3 + 2];
            cin[tid][128] = (_Float16)rx; cin[tid][129] = (_Float16)ry; cin[tid][130] = (_Float16)rz;
            gate[tid] = fsig_(fmaf(rx, e0w, fmaf(ry, e1w, fmaf(rz, e2w, ebw))));
        }
        __syncthreads();
        f32x4 acc[2][2];
        acc[0][0] = acc[0][1] = acc[1][0] = acc[1][1] = (f32x4){0.f, 0.f, 0.f, 0.f};
#pragma unroll
        for (int ks = 0; ks < 5; ++ks) {
            f16x8 a0 = *(const f16x8*)&cin[lc][ks * 32 + lg * 8];
            f16x8 a1 = *(const f16x8*)&cin[16 + lc][ks * 32 + lg * 8];
#pragma unroll
            for (int ti = 0; ti < 2; ++ti) {
                acc[0][ti] = MFMA16(a0, bw1[ti][ks], acc[0][ti]);
                acc[1][ti] = MFMA16(a1, bw1[ti][ks], acc[1][ti]);
            }
        }
#pragma unroll
        for (int ti = 0; ti < 2; ++ti) {
            int colc = (2 * w + ti) * 16 + lc;
            float bias = ti ? bias11 : bias10;
#pragma unroll
            for (int rt = 0; rt < 2; ++rt)
#pragma unroll
                for (int j = 0; j < 4; ++j)
                    h1[rt * 16 + lg * 4 + j][colc] = (_Float16)fsilu_(acc[rt][ti][j] + bias);
        }
        __syncthreads();
        // GEMM2 partial: wave w handles K-slice ks=w
        f32x4 c2[2];
        c2[0] = c2[1] = (f32x4){0.f, 0.f, 0.f, 0.f};
        {
            f16x8 a0 = *(const f16x8*)&h1[lc][w * 32 + lg * 8];
            f16x8 a1 = *(const f16x8*)&h1[16 + lc][w * 32 + lg * 8];
            c2[0] = MFMA16(a0, bw2, c2[0]);
            c2[1] = MFMA16(a1, bw2, c2[1]);
        }
#pragma unroll
        for (int rt = 0; rt < 2; ++rt)
#pragma unroll
            for (int j = 0; j < 4; ++j)
                pbuf[w][rt * 16 + lg * 4 + j][lc] = c2[rt][j];
        __syncthreads();
        if (tid < 32) {
            float d0 = pbuf[0][tid][0] + pbuf[1][tid][0] + pbuf[2][tid][0] + pbuf[3][tid][0] + b20;
            float d1 = pbuf[0][tid][1] + pbuf[1][tid][1] + pbuf[2][tid][1] + pbuf[3][tid][1] + b21;
            float d2 = pbuf[0][tid][2] + pbuf[1][tid][2] + pbuf[2][tid][2] + pbuf[3][tid][2] + b22;
            float ss = d0 * d0 + d1 * d1 + d2 * d2;
            float nrm = fmaxf(__builtin_amdgcn_sqrtf(ss), 1e-8f);
            float m = sc * __builtin_amdgcn_rcpf(nrm) * gate[tid];
            int r = row[e0 + tid];
            atomicAdd(&cnext[(size_t)r * 3 + 0], d0 * m);
            atomicAdd(&cnext[(size_t)r * 3 + 1], d1 * m);
            atomicAdd(&cnext[(size_t)r * 3 + 2], d2 * m);
        }
    }
}

// ---- edge: block-coop, reg weights; USE_MSG: write e_msg fp16 / else atomic agg ----
template <int USE_MSG>
__global__ __launch_bounds__(256)
void k_edge2(const _Float16* __restrict__ h16, const float* __restrict__ coords,
             float* __restrict__ agg, _Float16* __restrict__ emsg,
             const int* __restrict__ row, const int* __restrict__ col,
             const _Float16* __restrict__ w1T, const float* __restrict__ b1,
             const _Float16* __restrict__ w2T, const float* __restrict__ b2) {
    __shared__ __attribute__((aligned(16))) _Float16 cin[32][168];
    __shared__ __attribute__((aligned(16))) _Float16 h1[32][136];
    __shared__ __attribute__((aligned(16))) _Float16 msg[32][72];
    for (int i = threadIdx.x; i < 32 * 168; i += 256) (&cin[0][0])[i] = (_Float16)0.0f;
    int tid = threadIdx.x;
    int w = tid >> 6, lane = tid & 63, lc = lane & 15, lg = lane >> 4;
    f16x8 bw1[2][5];
#pragma unroll
    for (int ti = 0; ti < 2; ++ti)
#pragma unroll
        for (int ks = 0; ks < 5; ++ks)
            bw1[ti][ks] = *(const f16x8*)&w1T[(size_t)((2 * w + ti) * 16 + lc) * 168 + ks * 32 + lg * 8];
    f16x8 bw2[4];
#pragma unroll
    for (int ks = 0; ks < 4; ++ks)
        bw2[ks] = *(const f16x8*)&w2T[(size_t)(w * 16 + lc) * 136 + ks * 32 + lg * 8];
    float bias10 = b1[(2 * w) * 16 + lc], bias11 = b1[(2 * w + 1) * 16 + lc];
    float bias2 = b2[w * 16 + lc];
    __syncthreads();

    for (int tile = blockIdx.x; tile < NT_E; tile += gridDim.x) {
        int e0 = tile * 32;
        {
            int el = tid >> 3, part = tid & 7;
            int r = row[e0 + el], c = col[e0 + el];
            *(f16x8*)&cin[el][part * 8] = *(const f16x8*)&h16[(size_t)r * 64 + part * 8];
            *(f16x8*)&cin[el][64 + part * 8] = *(const f16x8*)&h16[(size_t)c * 64 + part * 8];
        }
        if (tid < 32) {
            int r = row[e0 + tid], c = col[e0 + tid];
            cin[tid][128] = (_Float16)(coords[r * 3 + 0] - coords[c * 3 + 0]);
            cin[tid][129] = (_Float16)(coords[r * 3 + 1] - coords[c * 3 + 1]);
            cin[tid][130] = (_Float16)(coords[r * 3 + 2] - coords[c * 3 + 2]);
        }
        __syncthreads();
        f32x4 acc[2][2];
        acc[0][0] = acc[0][1] = acc[1][0] = acc[1][1] = (f32x4){0.f, 0.f, 0.f, 0.f};
#pragma unroll
        for (int ks = 0; ks < 5; ++ks) {
            f16x8 a0 = *(const f16x8*)&cin[lc][ks * 32 + lg * 8];
            f16x8 a1 = *(const f16x8*)&cin[16 + lc][ks * 32 + lg * 8];
#pragma unroll
            for (int ti = 0; ti < 2; ++ti) {
                acc[0][ti] = MFMA16(a0, bw1[ti][ks], acc[0][ti]);
                acc[1][ti] = MFMA16(a1, bw1[ti][ks], acc[1][ti]);
            }
        }
#pragma unroll
        for (int ti = 0; ti < 2; ++ti) {
            int colc = (2 * w + ti) * 16 + lc;
            float bias = ti ? bias11 : bias10;
#pragma unroll
            for (int rt = 0; rt < 2; ++rt)
#pragma unroll
                for (int j = 0; j < 4; ++j)
                    h1[rt * 16 + lg * 4 + j][colc] = (_Float16)fsilu_(acc[rt][ti][j] + bias);
        }
        __syncthreads();
        f32x4 c2[2];
        c2[0] = c2[1] = (f32x4){0.f, 0.f, 0.f, 0.f};
#pragma unroll
        for (int ks = 0; ks < 4; ++ks) {
            f16x8 a0 = *(const f16x8*)&h1[lc][ks * 32 + lg * 8];
            f16x8 a1 = *(const f16x8*)&h1[16 + lc][ks * 32 + lg * 8];
            c2[0] = MFMA16(a0, bw2[ks], c2[0]);
            c2[1] = MFMA16(a1, bw2[ks], c2[1]);
        }
        if (USE_MSG) {
#pragma unroll
            for (int rt = 0; rt < 2; ++rt)
#pragma unroll
                for (int j = 0; j < 4; ++j)
                    msg[rt * 16 + lg * 4 + j][w * 16 + lc] = (_Float16)fsilu_(c2[rt][j] + bias2);
            __syncthreads();
            int r = tid >> 3, part = tid & 7;
            *(f16x8*)&emsg[(size_t)(e0 + r) * 64 + part * 8] = *(const f16x8*)&msg[r][part * 8];
        } else {
#pragma unroll
            for (int rt = 0; rt < 2; ++rt)
#pragma unroll
                for (int j = 0; j < 4; ++j)
                    atomicAdd(&agg[(size_t)row[e0 + rt * 16 + lg * 4 + j] * 64 + w * 16 + lc],
                              fsilu_(c2[rt][j] + bias2));
            __syncthreads();
        }
    }
}

// ---- node: CSR gather (or agg read) + block-coop MLP + residual + LN ----
template <int USE_MSG>
__global__ __launch_bounds__(256)
void k_node2(float* __restrict__ h32, _Float16* __restrict__ h16,
             const float* __restrict__ agg, const _Float16* __restrict__ emsg,
             const int* __restrict__ rowptr, const int* __restrict__ eperm,
             const _Float16* __restrict__ w1T, const float* __restrict__ b1,
             const _Float16* __restrict__ w2T, const float* __restrict__ b2) {
    __shared__ __attribute__((aligned(16))) _Float16 cin[32][136];
    __shared__ __attribute__((aligned(16))) _Float16 h1[32][136];
    __shared__ __attribute__((aligned(16))) float vbuf[32][64];
    int tid = threadIdx.x;
    int w = tid >> 6, lane = tid & 63, lc = lane & 15, lg = lane >> 4;
    f16x8 bw1[2][4], bw2[4];
#pragma unroll
    for (int ti = 0; ti < 2; ++ti)
#pragma unroll
        for (int ks = 0; ks < 4; ++ks)
            bw1[ti][ks] = *(const f16x8*)&w1T[(size_t)((2 * w + ti) * 16 + lc) * 136 + ks * 32 + lg * 8];
#pragma unroll
    for (int ks = 0; ks < 4; ++ks)
        bw2[ks] = *(const f16x8*)&w2T[(size_t)(w * 16 + lc) * 136 + ks * 32 + lg * 8];
    float bias10 = b1[(2 * w) * 16 + lc], bias11 = b1[(2 * w + 1) * 16 + lc];
    float bias2 = b2[w * 16 + lc];

    for (int tile = blockIdx.x; tile < NT_N; tile += gridDim.x) {
        int n0 = tile * 32;
        {
            int nl = tid >> 3, part = tid & 7;
            int n = n0 + nl;
            *(f16x8*)&cin[nl][part * 8] = *(const f16x8*)&h16[(size_t)n * 64 + part * 8];
            if (USE_MSG) {
                float a[8] = {0.f, 0.f, 0.f, 0.f, 0.f, 0.f, 0.f, 0.f};
                int s = rowptr[n], e = rowptr[n + 1];
                for (int jj = s; jj < e; ++jj) {
                    int eid = eperm[jj];
                    f16x8 m = *(const f16x8*)&emsg[(size_t)eid * 64 + part * 8];
#pragma unroll
                    for (int q = 0; q < 8; ++q) a[q] += (float)m[q];
                }
                f16x8 o;
#pragma unroll
                for (int q = 0; q < 8; ++q) o[q] = (_Float16)a[q];
                *(f16x8*)&cin[nl][64 + part * 8] = o;
            } else {
                f32x4 xx = *(const f32x4*)&agg[(size_t)n * 64 + part * 8];
                f32x4 yy = *(const f32x4*)&agg[(size_t)n * 64 + part * 8 + 4];
                f16x8 o;
                o[0] = (_Float16)xx[0]; o[1] = (_Float16)xx[1]; o[2] = (_Float16)xx[2]; o[3] = (_Float16)xx[3];
                o[4] = (_Float16)yy[0]; o[5] = (_Float16)yy[1]; o[6] = (_Float16)yy[2]; o[7] = (_Float16)yy[3];
                *(f16x8*)&cin[nl][64 + part * 8] = o;
            }
        }
        __syncthreads();
        f32x4 acc[2][2];
        acc[0][0] = acc[0][1] = acc[1][0] = acc[1][1] = (f32x4){0.f, 0.f, 0.f, 0.f};
#pragma unroll
        for (int ks = 0; ks < 4; ++ks) {
            f16x8 a0 = *(const f16x8*)&cin[lc][ks * 32 + lg * 8];
            f16x8 a1 = *(const f16x8*)&cin[16 + lc][ks * 32 + lg * 8];
#pragma unroll
            for (int ti = 0; ti < 2; ++ti) {
                acc[0][ti] = MFMA16(a0, bw1[ti][ks], acc[0][ti]);
                acc[1][ti] = MFMA16(a1, bw1[ti][ks], acc[1][ti]);
            }
        }
#pragma unroll
        for (int ti = 0; ti < 2; ++ti) {
            int colc = (2 * w + ti) * 16 + lc;
            float bias = ti ? bias11 : bias10;
#pragma unroll
            for (int rt = 0; rt < 2; ++rt)
#pragma unroll
                for (int j = 0; j < 4; ++j)
                    h1[rt * 16 + lg * 4 + j][colc] = (_Float16)fsilu_(acc[rt][ti][j] + bias);
        }
        __syncthreads();
        f32x4 c2[2];
        c2[0] = c2[1] = (f32x4){0.f, 0.f, 0.f, 0.f};
#pragma unroll
        for (int ks = 0; ks < 4; ++ks) {
            f16x8 a0 = *(const f16x8*)&h1[lc][ks * 32 + lg * 8];
            f16x8 a1 = *(const f16x8*)&h1[16 + lc][ks * 32 + lg * 8];
            c2[0] = MFMA16(a0, bw2[ks], c2[0]);
            c2[1] = MFMA16(a1, bw2[ks], c2[1]);
        }
#pragma unroll
        for (int rt = 0; rt < 2; ++rt)
#pragma unroll
            for (int j = 0; j < 4; ++j) {
                int rl = rt * 16 + lg * 4 + j, colc = w * 16 + lc;
                vbuf[rl][colc] = h32[(size_t)(n0 + rl) * 64 + colc] + c2[rt][j] + bias2;
            }
        __syncthreads();
        {
            int r = w * 8 + (lane >> 3), sub = lane & 7;
            f32x4 v0 = *(const f32x4*)&vbuf[r][sub * 8];
            f32x4 v1 = *(const f32x4*)&vbuf[r][sub * 8 + 4];
            float s = v0[0] + v0[1] + v0[2] + v0[3] + v1[0] + v1[1] + v1[2] + v1[3];
            float sq = v0[0]*v0[0] + v0[1]*v0[1] + v0[2]*v0[2] + v0[3]*v0[3]
                     + v1[0]*v1[0] + v1[1]*v1[1] + v1[2]*v1[2] + v1[3]*v1[3];
            s += __shfl_xor(s, 1); s += __shfl_xor(s, 2); s += __shfl_xor(s, 4);
            sq += __shfl_xor(sq, 1); sq += __shfl_xor(sq, 2); sq += __shfl_xor(sq, 4);
            float mu = s * (1.0f / 64.0f);
            float var = sq * (1.0f / 64.0f) - mu * mu;
            float rs = __builtin_amdgcn_rcpf(__builtin_amdgcn_sqrtf(var + 1e-5f));
            size_t base = (size_t)(n0 + r) * 64 + sub * 8;
            f32x4 o0, o1; f16x8 oh;
#pragma unroll
            for (int i = 0; i < 4; ++i) {
                o0[i] = (v0[i] - mu) * rs;
                o1[i] = (v1[i] - mu) * rs;
                oh[i] = (_Float16)o0[i];
                oh[4 + i] = (_Float16)o1[i];
            }
            *(f32x4*)&h32[base] = o0;
            *(f32x4*)&h32[base + 4] = o1;
            *(f16x8*)&h16[base] = oh;
        }
        __syncthreads();
    }
}

__global__ void k_pool_seg(const float* __restrict__ h, const int* __restrict__ batch,
                           float* __restrict__ pooled, float* __restrict__ cnt) {
    int lane = threadIdx.x & 63;
    int wid = blockIdx.x * (blockDim.x >> 6) + (threadIdx.x >> 6);
    int nwav = gridDim.x * (blockDim.x >> 6);
    int chunk = (NN + nwav - 1) / nwav;
    int s = wid * chunk;
    if (s >= NN) return;
    int e = s + chunk; if (e > NN) e = NN;
    int g = batch[s];
    float acc = 0.0f, c = 0.0f;
    for (int n = s; n < e; ++n) {
        int b = batch[n];
        if (b != g) {
            atomicAdd(&pooled[g * 64 + lane], acc);
            if (lane == 0) atomicAdd(&cnt[g], c);
            acc = 0.0f; c = 0.0f; g = b;
        }
        acc += h[(size_t)n * 64 + lane];
        c += 1.0f;
    }
    atomicAdd(&pooled[g * 64 + lane], acc);
    if (lane == 0) atomicAdd(&cnt[g], c);
}

__global__ void k_final(const float* __restrict__ pooled, const float* __restrict__ cnt,
                        const float* __restrict__ ow, const float* __restrict__ ob,
                        float* __restrict__ out) {
    __shared__ float red[2];
    int g = blockIdx.x, o = threadIdx.x;  // 128 threads
    float c = fmaxf(cnt[g], 1.0f);
    float acc = ob[o];
#pragma unroll
    for (int j = 0; j < 64; ++j) {
        float pm = fmaxf(pooled[g * 64 + j] / c, 0.0f);
        acc = fmaf(pm, ow[j * 128 + o], acc);
    }
    float ss = acc * acc;
#pragma unroll
    for (int off = 32; off > 0; off >>= 1) ss += __shfl_xor(ss, off);
    if ((o & 63) == 0) red[o >> 6] = ss;
    __syncthreads();
    float nrm = sqrtf(red[0] + red[1]);
    out[g * 128 + o] = acc / fmaxf(nrm, 1e-12f);
}

extern "C" void kernel_launch(void* const* d_in, const int* in_sizes, int n_in,
                              void* d_out, int out_size, void* d_ws, size_t ws_size,
                              hipStream_t stream) {
    const float* x         = (const float*)d_in[0];
    const float* coords_in = (const float*)d_in[1];
    const float* in_w      = (const float*)d_in[2];
    const float* in_b      = (const float*)d_in[3];
    const float* coord_w1  = (const float*)d_in[4];
    const float* coord_b1  = (const float*)d_in[5];
    const float* coord_w2  = (const float*)d_in[6];
    const float* coord_b2  = (const float*)d_in[7];
    const float* ew_w      = (const float*)d_in[8];
    const float* ew_b      = (const float*)d_in[9];
    const float* cn_scale  = (const float*)d_in[10];
    const float* edge_w1   = (const float*)d_in[11];
    const float* edge_b1   = (const float*)d_in[12];
    const float* edge_w2   = (const float*)d_in[13];
    const float* edge_b2   = (const float*)d_in[14];
    const float* node_w1   = (const float*)d_in[15];
    const float* node_b1   = (const float*)d_in[16];
    const float* node_w2   = (const float*)d_in[17];
    const float* node_b2   = (const float*)d_in[18];
    const float* out_w     = (const float*)d_in[19];
    const float* out_b     = (const float*)d_in[20];
    const int* ei          = (const int*)d_in[21];
    const int* batch       = (const int*)d_in[22];
    const int* row = ei;
    const int* col = ei + NE;

    char* wp = (char*)d_ws;
    float* h32    = (float*)wp; wp += (size_t)NN * 64 * 4;
    float* cA     = (float*)wp; wp += (size_t)NN * 3 * 4;
    float* cB     = (float*)wp; wp += (size_t)NN * 3 * 4;
    float* pooled = (float*)wp; wp += (size_t)NG * 64 * 4;
    float* cnt    = (float*)wp; wp += (size_t)NG * 4;
    _Float16* h16  = (_Float16*)wp; wp += (size_t)NN * 64 * 2;
    _Float16* cw1T = (_Float16*)wp; wp += (size_t)NL * SEG0 * 2;
    _Float16* ew1T = (_Float16*)wp; wp += (size_t)NL * SEG1 * 2;
    _Float16* ew2T = (_Float16*)wp; wp += (size_t)NL * SEG2 * 2;
    _Float16* nw1T = (_Float16*)wp; wp += (size_t)NL * SEG3 * 2;
    _Float16* nw2T = (_Float16*)wp; wp += (size_t)NL * SEG4 * 2;
    _Float16* cw2T = (_Float16*)wp; wp += (size_t)NL * SEG5 * 2;
    // branch region (union)
    char* br = wp;
    int* deg       = (int*)br;
    int* rowptr    = deg + NN;
    int* pos       = rowptr + (NN + 2);
    int* eperm     = pos + NN;
    _Float16* emsg = (_Float16*)(eperm + NE);
    size_t csr_need = ((char*)(emsg + (size_t)NE * 64)) - (char*)d_ws;
    float* agg = (float*)br;  // legacy path
    size_t legacy_need = (br + (size_t)NN * 64 * 4) - (char*)d_ws;
    bool use_msg = (ws_size >= csr_need);

    if (use_msg) {
        hipMemsetAsync(deg, 0, (size_t)NN * 4, stream);
        k_hist<<<(NE + 255) / 256, 256, 0, stream>>>(row, deg);
        k_scan<<<1, 256, 0, stream>>>(deg, rowptr);
        hipMemcpyAsync(pos, rowptr, (size_t)NN * 4, hipMemcpyDeviceToDevice, stream);
        k_scatter<<<(NE + 255) / 256, 256, 0, stream>>>(row, pos, eperm);
    }
    k_prep_all<<<(NL * SEGTOT + 255) / 256, 256, 0, stream>>>(
        coord_w1, edge_w1, edge_w2, node_w1, node_w2, coord_w2,
        cw1T, ew1T, ew2T, nw1T, nw2T, cw2T);
    k_init_h<<<(NN * 64 + 255) / 256, 256, 0, stream>>>(x, in_w, in_b, h32, h16);

    const float* cur = coords_in;
    float* nxt = cA;
    for (int l = 0; l < NL; ++l) {
        hipMemcpyAsync(nxt, cur, (size_t)NN * 3 * sizeof(float), hipMemcpyDeviceToDevice, stream);
        k_coord2<<<2048, 256, 0, stream>>>(h16, cur, nxt, row, col,
            cw1T + (size_t)l * SEG0, coord_b1 + l * 128,
            cw2T + (size_t)l * SEG5, coord_b2 + l * 3,
            ew_w + l * 3, ew_b + l, cn_scale + l);
        if (use_msg) {
            k_edge2<1><<<2048, 256, 0, stream>>>(h16, nxt, nullptr, emsg, row, col,
                ew1T + (size_t)l * SEG1, edge_b1 + l * 128,
                ew2T + (size_t)l * SEG2, edge_b2 + l * 64);
            k_node2<1><<<1024, 256, 0, stream>>>(h32, h16, nullptr, emsg, rowptr, eperm,
                nw1T + (size_t)l * SEG3, node_b1 + l * 128,
                nw2T + (size_t)l * SEG4, node_b2 + l * 64);
        } else {
            hipMemsetAsync(agg, 0, (size_t)NN * 64 * 4, stream);
            k_edge2<0><<<2048, 256, 0, stream>>>(h16, nxt, agg, nullptr, row, col,
                ew1T + (size_t)l * SEG1, edge_b1 + l * 128,
                ew2T + (size_t)l * SEG2, edge_b2 + l * 64);
            k_node2<0><<<1024, 256, 0, stream>>>(h32, h16, agg, nullptr, nullptr, nullptr,
                nw1T + (size_t)l * SEG3, node_b1 + l * 128,
                nw2T + (size_t)l * SEG4, node_b2 + l * 64);
        }
        cur = nxt;
        nxt = (nxt == cA) ? cB : cA;
    }
    hipMemsetAsync(pooled, 0, (size_t)(NG * 64 + NG) * sizeof(float), stream);
    k_pool_seg<<<512, 256, 0, stream>>>(h32, batch, pooled, cnt);
    k_final<<<NG, 128, 0, stream>>>(pooled, cnt, out_w, out_b, (float*)d_out);
    (void)legacy_need;
}

// Round 6
// 1346.063 us; speedup vs baseline: 57.7714x; 1.2916x over previous
//
#include <hip/hip_runtime.h>
#include <math.h>

#define NN 100000
#define NE 1000000
#define NG 64
#define NL 4
#define NT_E (NE / 32)
#define NT_N (NN / 32)

typedef __attribute__((ext_vector_type(8))) _Float16 f16x8;
typedef __attribute__((ext_vector_type(4))) float f32x4;

#define MFMA16(a, b, c) __builtin_amdgcn_mfma_f32_16x16x32_f16(a, b, c, 0, 0, 0)
#define LOG2E 1.44269504088896340f
__device__ __forceinline__ float fsig_(float x) {
    return __builtin_amdgcn_rcpf(1.0f + __builtin_amdgcn_exp2f(-LOG2E * x));
}
__device__ __forceinline__ float fsilu_(float x) { return x * fsig_(x); }

__global__ void k_init_h(const float* __restrict__ x, const float* __restrict__ in_w,
                         const float* __restrict__ in_b, float* __restrict__ h32,
                         _Float16* __restrict__ h16) {
    int idx = blockIdx.x * blockDim.x + threadIdx.x;
    if (idx >= NN * 64) return;
    int n = idx >> 6, j = idx & 63;
    float v = fmaf(x[n], in_w[j], in_b[j]);
    h32[idx] = v;
    h16[idx] = (_Float16)v;
}

// transpose + fp16 + zero-pad all weight families x 4 layers
#define SEG0 21504  // 128*168 cw1T
#define SEG1 21504  // ew1T
#define SEG2 8704   // 64*136  ew2T
#define SEG3 17408  // 128*136 nw1T
#define SEG4 8704   // nw2T
#define SEG5 2176   // 16*136  cw2T (O=3 padded to 16)
#define SEGTOT (SEG0 + SEG1 + SEG2 + SEG3 + SEG4 + SEG5)
__global__ void k_prep_all(const float* __restrict__ cw1, const float* __restrict__ ew1,
                           const float* __restrict__ ew2, const float* __restrict__ nw1,
                           const float* __restrict__ nw2, const float* __restrict__ cw2,
                           _Float16* __restrict__ cw1T, _Float16* __restrict__ ew1T,
                           _Float16* __restrict__ ew2T, _Float16* __restrict__ nw1T,
                           _Float16* __restrict__ nw2T, _Float16* __restrict__ cw2T) {
    int i = blockIdx.x * blockDim.x + threadIdx.x;
    if (i >= NL * SEGTOT) return;
    int l = i / SEGTOT, r = i - l * SEGTOT;
    const float* src; _Float16* dst; int K, O, SD, j;
    if (r < SEG0) { src = cw1 + (size_t)l * 131 * 128; dst = cw1T + (size_t)l * SEG0; K = 131; O = 128; SD = 168; j = r; }
    else if ((r -= SEG0) < SEG1) { src = ew1 + (size_t)l * 131 * 128; dst = ew1T + (size_t)l * SEG1; K = 131; O = 128; SD = 168; j = r; }
    else if ((r -= SEG1) < SEG2) { src = ew2 + (size_t)l * 128 * 64; dst = ew2T + (size_t)l * SEG2; K = 128; O = 64; SD = 136; j = r; }
    else if ((r -= SEG2) < SEG3) { src = nw1 + (size_t)l * 128 * 128; dst = nw1T + (size_t)l * SEG3; K = 128; O = 128; SD = 136; j = r; }
    else if ((r -= SEG3) < SEG4) { src = nw2 + (size_t)l * 128 * 64; dst = nw2T + (size_t)l * SEG4; K = 128; O = 64; SD = 136; j = r; }
    else {
        r -= SEG4;
        const float* s2 = cw2 + (size_t)l * 128 * 3;
        int o = r / 136, k = r - o * 136;
        cw2T[(size_t)l * SEG5 + r] = (o < 3 && k < 128) ? (_Float16)s2[(size_t)k * 3 + o] : (_Float16)0.0f;
        return;
    }
    int o = j / SD, k = j - o * SD;
    dst[j] = (k < K) ? (_Float16)src[(size_t)k * O + o] : (_Float16)0.0f;
}

// ---- CSR build (once per launch) ----
__global__ void k_hist(const int* __restrict__ row, int* __restrict__ deg) {
    int e = blockIdx.x * blockDim.x + threadIdx.x;
    if (e < NE) atomicAdd(&deg[row[e]], 1);
}
__global__ void k_scan(const int* __restrict__ deg, int* __restrict__ rowptr) {
    __shared__ int ss[256];
    int t = threadIdx.x;
    const int CH = (NN + 255) / 256;
    int base = t * CH;
    int end = base + CH; if (end > NN) end = NN;
    int s = 0;
    for (int i = base; i < end; ++i) s += deg[i];
    ss[t] = s;
    __syncthreads();
    if (t == 0) {
        int run = 0;
        for (int i = 0; i < 256; ++i) { int v = ss[i]; ss[i] = run; run += v; }
    }
    __syncthreads();
    int run = ss[t];
    for (int i = base; i < end; ++i) { rowptr[i] = run; run += deg[i]; }
    if (t == 0) rowptr[NN] = NE;
}
// permute row/col into CSR slot order
__global__ void k_scatter2(const int* __restrict__ row, const int* __restrict__ col,
                           int* __restrict__ pos, int* __restrict__ rowP,
                           int* __restrict__ colP) {
    int e = blockIdx.x * blockDim.x + threadIdx.x;
    if (e < NE) {
        int r = row[e];
        int p = atomicAdd(&pos[r], 1);
        rowP[p] = r;
        colP[p] = col[e];
    }
}

// ---- coord: block-coop GEMM1 + ks-split GEMM2; CSR=1 -> write deltas[slot] coalesced
template <int CSR>
__global__ __launch_bounds__(256)
void k_coord3(const _Float16* __restrict__ h16,
              const float* __restrict__ ccur, float* __restrict__ cnext,
              const int* __restrict__ rowP, const int* __restrict__ colP,
              float4* __restrict__ deltas,
              const _Float16* __restrict__ w1T, const float* __restrict__ b1,
              const _Float16* __restrict__ w2T, const float* __restrict__ b2,
              const float* __restrict__ eww, const float* __restrict__ ewb,
              const float* __restrict__ cns) {
    __shared__ __attribute__((aligned(16))) _Float16 cin[32][168];
    __shared__ __attribute__((aligned(16))) _Float16 h1[32][136];
    __shared__ __attribute__((aligned(16))) float pbuf[4][32][17];
    __shared__ float gate[32];
    for (int i = threadIdx.x; i < 32 * 168; i += 256) (&cin[0][0])[i] = (_Float16)0.0f;
    int tid = threadIdx.x;
    int w = tid >> 6, lane = tid & 63, lc = lane & 15, lg = lane >> 4;
    float e0w = eww[0], e1w = eww[1], e2w = eww[2], ebw = ewb[0], sc = cns[0];
    float b20 = b2[0], b21 = b2[1], b22 = b2[2];
    f16x8 bw1[2][5];
#pragma unroll
    for (int ti = 0; ti < 2; ++ti)
#pragma unroll
        for (int ks = 0; ks < 5; ++ks)
            bw1[ti][ks] = *(const f16x8*)&w1T[(size_t)((2 * w + ti) * 16 + lc) * 168 + ks * 32 + lg * 8];
    f16x8 bw2 = *(const f16x8*)&w2T[(size_t)lc * 136 + w * 32 + lg * 8];
    float bias10 = b1[(2 * w) * 16 + lc], bias11 = b1[(2 * w + 1) * 16 + lc];
    __syncthreads();

    for (int tile = blockIdx.x; tile < NT_E; tile += gridDim.x) {
        int e0 = tile * 32;
        {
            int el = tid >> 3, part = tid & 7;
            int r = rowP[e0 + el], c = colP[e0 + el];
            *(f16x8*)&cin[el][part * 8] = *(const f16x8*)&h16[(size_t)r * 64 + part * 8];
            *(f16x8*)&cin[el][64 + part * 8] = *(const f16x8*)&h16[(size_t)c * 64 + part * 8];
        }
        if (tid < 32) {
            int r = rowP[e0 + tid], c = colP[e0 + tid];
            float rx = ccur[r * 3 + 0] - ccur[c * 3 + 0];
            float ry = ccur[r * 3 + 1] - ccur[c * 3 + 1];
            float rz = ccur[r * 3 + 2] - ccur[c * 3 + 2];
            cin[tid][128] = (_Float16)rx; cin[tid][129] = (_Float16)ry; cin[tid][130] = (_Float16)rz;
            gate[tid] = fsig_(fmaf(rx, e0w, fmaf(ry, e1w, fmaf(rz, e2w, ebw))));
        }
        __syncthreads();
        f32x4 acc[2][2];
        acc[0][0] = acc[0][1] = acc[1][0] = acc[1][1] = (f32x4){0.f, 0.f, 0.f, 0.f};
#pragma unroll
        for (int ks = 0; ks < 5; ++ks) {
            f16x8 a0 = *(const f16x8*)&cin[lc][ks * 32 + lg * 8];
            f16x8 a1 = *(const f16x8*)&cin[16 + lc][ks * 32 + lg * 8];
#pragma unroll
            for (int ti = 0; ti < 2; ++ti) {
                acc[0][ti] = MFMA16(a0, bw1[ti][ks], acc[0][ti]);
                acc[1][ti] = MFMA16(a1, bw1[ti][ks], acc[1][ti]);
            }
        }
#pragma unroll
        for (int ti = 0; ti < 2; ++ti) {
            int colc = (2 * w + ti) * 16 + lc;
            float bias = ti ? bias11 : bias10;
#pragma unroll
            for (int rt = 0; rt < 2; ++rt)
#pragma unroll
                for (int j = 0; j < 4; ++j)
                    h1[rt * 16 + lg * 4 + j][colc] = (_Float16)fsilu_(acc[rt][ti][j] + bias);
        }
        __syncthreads();
        f32x4 c2[2];
        c2[0] = c2[1] = (f32x4){0.f, 0.f, 0.f, 0.f};
        {
            f16x8 a0 = *(const f16x8*)&h1[lc][w * 32 + lg * 8];
            f16x8 a1 = *(const f16x8*)&h1[16 + lc][w * 32 + lg * 8];
            c2[0] = MFMA16(a0, bw2, c2[0]);
            c2[1] = MFMA16(a1, bw2, c2[1]);
        }
#pragma unroll
        for (int rt = 0; rt < 2; ++rt)
#pragma unroll
            for (int j = 0; j < 4; ++j)
                pbuf[w][rt * 16 + lg * 4 + j][lc] = c2[rt][j];
        __syncthreads();
        if (tid < 32) {
            float d0 = pbuf[0][tid][0] + pbuf[1][tid][0] + pbuf[2][tid][0] + pbuf[3][tid][0] + b20;
            float d1 = pbuf[0][tid][1] + pbuf[1][tid][1] + pbuf[2][tid][1] + pbuf[3][tid][1] + b21;
            float d2 = pbuf[0][tid][2] + pbuf[1][tid][2] + pbuf[2][tid][2] + pbuf[3][tid][2] + b22;
            float ss = d0 * d0 + d1 * d1 + d2 * d2;
            float nrm = fmaxf(__builtin_amdgcn_sqrtf(ss), 1e-8f);
            float m = sc * __builtin_amdgcn_rcpf(nrm) * gate[tid];
            if (CSR) {
                deltas[e0 + tid] = make_float4(d0 * m, d1 * m, d2 * m, 0.0f);
            } else {
                int r = rowP[e0 + tid];
                atomicAdd(&cnext[(size_t)r * 3 + 0], d0 * m);
                atomicAdd(&cnext[(size_t)r * 3 + 1], d1 * m);
                atomicAdd(&cnext[(size_t)r * 3 + 2], d2 * m);
            }
        }
    }
}

// cnext[n] = ccur[n] + sum of this node's contiguous delta slots (no atomics)
__global__ void k_coord_apply(const float* __restrict__ ccur, float* __restrict__ cnext,
                              const int* __restrict__ rowptr,
                              const float4* __restrict__ deltas) {
    int n = blockIdx.x * blockDim.x + threadIdx.x;
    if (n >= NN) return;
    int s = rowptr[n], e = rowptr[n + 1];
    float d0 = 0.f, d1 = 0.f, d2 = 0.f;
    for (int j = s; j < e; ++j) {
        float4 d = deltas[j];
        d0 += d.x; d1 += d.y; d2 += d.z;
    }
    cnext[(size_t)n * 3 + 0] = ccur[(size_t)n * 3 + 0] + d0;
    cnext[(size_t)n * 3 + 1] = ccur[(size_t)n * 3 + 1] + d1;
    cnext[(size_t)n * 3 + 2] = ccur[(size_t)n * 3 + 2] + d2;
}

// ---- edge: CSR=1 -> write emsgS[slot] coalesced; CSR=0 -> atomic agg
template <int CSR>
__global__ __launch_bounds__(256)
void k_edge3(const _Float16* __restrict__ h16, const float* __restrict__ coords,
             float* __restrict__ agg, _Float16* __restrict__ emsgS,
             const int* __restrict__ rowP, const int* __restrict__ colP,
             const _Float16* __restrict__ w1T, const float* __restrict__ b1,
             const _Float16* __restrict__ w2T, const float* __restrict__ b2) {
    __shared__ __attribute__((aligned(16))) _Float16 cin[32][168];
    __shared__ __attribute__((aligned(16))) _Float16 h1[32][136];
    __shared__ __attribute__((aligned(16))) _Float16 msg[32][72];
    for (int i = threadIdx.x; i < 32 * 168; i += 256) (&cin[0][0])[i] = (_Float16)0.0f;
    int tid = threadIdx.x;
    int w = tid >> 6, lane = tid & 63, lc = lane & 15, lg = lane >> 4;
    f16x8 bw1[2][5];
#pragma unroll
    for (int ti = 0; ti < 2; ++ti)
#pragma unroll
        for (int ks = 0; ks < 5; ++ks)
            bw1[ti][ks] = *(const f16x8*)&w1T[(size_t)((2 * w + ti) * 16 + lc) * 168 + ks * 32 + lg * 8];
    f16x8 bw2[4];
#pragma unroll
    for (int ks = 0; ks < 4; ++ks)
        bw2[ks] = *(const f16x8*)&w2T[(size_t)(w * 16 + lc) * 136 + ks * 32 + lg * 8];
    float bias10 = b1[(2 * w) * 16 + lc], bias11 = b1[(2 * w + 1) * 16 + lc];
    float bias2 = b2[w * 16 + lc];
    __syncthreads();

    for (int tile = blockIdx.x; tile < NT_E; tile += gridDim.x) {
        int e0 = tile * 32;
        {
            int el = tid >> 3, part = tid & 7;
            int r = rowP[e0 + el], c = colP[e0 + el];
            *(f16x8*)&cin[el][part * 8] = *(const f16x8*)&h16[(size_t)r * 64 + part * 8];
            *(f16x8*)&cin[el][64 + part * 8] = *(const f16x8*)&h16[(size_t)c * 64 + part * 8];
        }
        if (tid < 32) {
            int r = rowP[e0 + tid], c = colP[e0 + tid];
            cin[tid][128] = (_Float16)(coords[r * 3 + 0] - coords[c * 3 + 0]);
            cin[tid][129] = (_Float16)(coords[r * 3 + 1] - coords[c * 3 + 1]);
            cin[tid][130] = (_Float16)(coords[r * 3 + 2] - coords[c * 3 + 2]);
        }
        __syncthreads();
        f32x4 acc[2][2];
        acc[0][0] = acc[0][1] = acc[1][0] = acc[1][1] = (f32x4){0.f, 0.f, 0.f, 0.f};
#pragma unroll
        for (int ks = 0; ks < 5; ++ks) {
            f16x8 a0 = *(const f16x8*)&cin[lc][ks * 32 + lg * 8];
            f16x8 a1 = *(const f16x8*)&cin[16 + lc][ks * 32 + lg * 8];
#pragma unroll
            for (int ti = 0; ti < 2; ++ti) {
                acc[0][ti] = MFMA16(a0, bw1[ti][ks], acc[0][ti]);
                acc[1][ti] = MFMA16(a1, bw1[ti][ks], acc[1][ti]);
            }
        }
#pragma unroll
        for (int ti = 0; ti < 2; ++ti) {
            int colc = (2 * w + ti) * 16 + lc;
            float bias = ti ? bias11 : bias10;
#pragma unroll
            for (int rt = 0; rt < 2; ++rt)
#pragma unroll
                for (int j = 0; j < 4; ++j)
                    h1[rt * 16 + lg * 4 + j][colc] = (_Float16)fsilu_(acc[rt][ti][j] + bias);
        }
        __syncthreads();
        f32x4 c2[2];
        c2[0] = c2[1] = (f32x4){0.f, 0.f, 0.f, 0.f};
#pragma unroll
        for (int ks = 0; ks < 4; ++ks) {
            f16x8 a0 = *(const f16x8*)&h1[lc][ks * 32 + lg * 8];
            f16x8 a1 = *(const f16x8*)&h1[16 + lc][ks * 32 + lg * 8];
            c2[0] = MFMA16(a0, bw2[ks], c2[0]);
            c2[1] = MFMA16(a1, bw2[ks], c2[1]);
        }
        if (CSR) {
#pragma unroll
            for (int rt = 0; rt < 2; ++rt)
#pragma unroll
                for (int j = 0; j < 4; ++j)
                    msg[rt * 16 + lg * 4 + j][w * 16 + lc] = (_Float16)fsilu_(c2[rt][j] + bias2);
            __syncthreads();
            int r = tid >> 3, part = tid & 7;
            *(f16x8*)&emsgS[(size_t)(e0 + r) * 64 + part * 8] = *(const f16x8*)&msg[r][part * 8];
        } else {
#pragma unroll
            for (int rt = 0; rt < 2; ++rt)
#pragma unroll
                for (int j = 0; j < 4; ++j)
                    atomicAdd(&agg[(size_t)rowP[e0 + rt * 16 + lg * 4 + j] * 64 + w * 16 + lc],
                              fsilu_(c2[rt][j] + bias2));
            __syncthreads();
        }
    }
}

// ---- node: CSR=1 -> contiguous emsgS range per node; else agg read
template <int CSR>
__global__ __launch_bounds__(256)
void k_node3(float* __restrict__ h32, _Float16* __restrict__ h16,
             const float* __restrict__ agg, const _Float16* __restrict__ emsgS,
             const int* __restrict__ rowptr,
             const _Float16* __restrict__ w1T, const float* __restrict__ b1,
             const _Float16* __restrict__ w2T, const float* __restrict__ b2) {
    __shared__ __attribute__((aligned(16))) _Float16 cin[32][136];
    __shared__ __attribute__((aligned(16))) _Float16 h1[32][136];
    __shared__ __attribute__((aligned(16))) float vbuf[32][64];
    int tid = threadIdx.x;
    int w = tid >> 6, lane = tid & 63, lc = lane & 15, lg = lane >> 4;
    f16x8 bw1[2][4], bw2[4];
#pragma unroll
    for (int ti = 0; ti < 2; ++ti)
#pragma unroll
        for (int ks = 0; ks < 4; ++ks)
            bw1[ti][ks] = *(const f16x8*)&w1T[(size_t)((2 * w + ti) * 16 + lc) * 136 + ks * 32 + lg * 8];
#pragma unroll
    for (int ks = 0; ks < 4; ++ks)
        bw2[ks] = *(const f16x8*)&w2T[(size_t)(w * 16 + lc) * 136 + ks * 32 + lg * 8];
    float bias10 = b1[(2 * w) * 16 + lc], bias11 = b1[(2 * w + 1) * 16 + lc];
    float bias2 = b2[w * 16 + lc];

    for (int tile = blockIdx.x; tile < NT_N; tile += gridDim.x) {
        int n0 = tile * 32;
        {
            int nl = tid >> 3, part = tid & 7;
            int n = n0 + nl;
            *(f16x8*)&cin[nl][part * 8] = *(const f16x8*)&h16[(size_t)n * 64 + part * 8];
            if (CSR) {
                float a[8] = {0.f, 0.f, 0.f, 0.f, 0.f, 0.f, 0.f, 0.f};
                int s = rowptr[n], e = rowptr[n + 1];
                for (int jj = s; jj < e; ++jj) {
                    f16x8 m = *(const f16x8*)&emsgS[(size_t)jj * 64 + part * 8];
#pragma unroll
                    for (int q = 0; q < 8; ++q) a[q] += (float)m[q];
                }
                f16x8 o;
#pragma unroll
                for (int q = 0; q < 8; ++q) o[q] = (_Float16)a[q];
                *(f16x8*)&cin[nl][64 + part * 8] = o;
            } else {
                f32x4 xx = *(const f32x4*)&agg[(size_t)n * 64 + part * 8];
                f32x4 yy = *(const f32x4*)&agg[(size_t)n * 64 + part * 8 + 4];
                f16x8 o;
                o[0] = (_Float16)xx[0]; o[1] = (_Float16)xx[1]; o[2] = (_Float16)xx[2]; o[3] = (_Float16)xx[3];
                o[4] = (_Float16)yy[0]; o[5] = (_Float16)yy[1]; o[6] = (_Float16)yy[2]; o[7] = (_Float16)yy[3];
                *(f16x8*)&cin[nl][64 + part * 8] = o;
            }
        }
        __syncthreads();
        f32x4 acc[2][2];
        acc[0][0] = acc[0][1] = acc[1][0] = acc[1][1] = (f32x4){0.f, 0.f, 0.f, 0.f};
#pragma unroll
        for (int ks = 0; ks < 4; ++ks) {
            f16x8 a0 = *(const f16x8*)&cin[lc][ks * 32 + lg * 8];
            f16x8 a1 = *(const f16x8*)&cin[16 + lc][ks * 32 + lg * 8];
#pragma unroll
            for (int ti = 0; ti < 2; ++ti) {
                acc[0][ti] = MFMA16(a0, bw1[ti][ks], acc[0][ti]);
                acc[1][ti] = MFMA16(a1, bw1[ti][ks], acc[1][ti]);
            }
        }
#pragma unroll
        for (int ti = 0; ti < 2; ++ti) {
            int colc = (2 * w + ti) * 16 + lc;
            float bias = ti ? bias11 : bias10;
#pragma unroll
            for (int rt = 0; rt < 2; ++rt)
#pragma unroll
                for (int j = 0; j < 4; ++j)
                    h1[rt * 16 + lg * 4 + j][colc] = (_Float16)fsilu_(acc[rt][ti][j] + bias);
        }
        __syncthreads();
        f32x4 c2[2];
        c2[0] = c2[1] = (f32x4){0.f, 0.f, 0.f, 0.f};
#pragma unroll
        for (int ks = 0; ks < 4; ++ks) {
            f16x8 a0 = *(const f16x8*)&h1[lc][ks * 32 + lg * 8];
            f16x8 a1 = *(const f16x8*)&h1[16 + lc][ks * 32 + lg * 8];
            c2[0] = MFMA16(a0, bw2[ks], c2[0]);
            c2[1] = MFMA16(a1, bw2[ks], c2[1]);
        }
#pragma unroll
        for (int rt = 0; rt < 2; ++rt)
#pragma unroll
            for (int j = 0; j < 4; ++j) {
                int rl = rt * 16 + lg * 4 + j, colc = w * 16 + lc;
                vbuf[rl][colc] = h32[(size_t)(n0 + rl) * 64 + colc] + c2[rt][j] + bias2;
            }
        __syncthreads();
        {
            int r = w * 8 + (lane >> 3), sub = lane & 7;
            f32x4 v0 = *(const f32x4*)&vbuf[r][sub * 8];
            f32x4 v1 = *(const f32x4*)&vbuf[r][sub * 8 + 4];
            float s = v0[0] + v0[1] + v0[2] + v0[3] + v1[0] + v1[1] + v1[2] + v1[3];
            float sq = v0[0]*v0[0] + v0[1]*v0[1] + v0[2]*v0[2] + v0[3]*v0[3]
                     + v1[0]*v1[0] + v1[1]*v1[1] + v1[2]*v1[2] + v1[3]*v1[3];
            s += __shfl_xor(s, 1); s += __shfl_xor(s, 2); s += __shfl_xor(s, 4);
            sq += __shfl_xor(sq, 1); sq += __shfl_xor(sq, 2); sq += __shfl_xor(sq, 4);
            float mu = s * (1.0f / 64.0f);
            float var = sq * (1.0f / 64.0f) - mu * mu;
            float rs = __builtin_amdgcn_rcpf(__builtin_amdgcn_sqrtf(var + 1e-5f));
            size_t base = (size_t)(n0 + r) * 64 + sub * 8;
            f32x4 o0, o1; f16x8 oh;
#pragma unroll
            for (int i = 0; i < 4; ++i) {
                o0[i] = (v0[i] - mu) * rs;
                o1[i] = (v1[i] - mu) * rs;
                oh[i] = (_Float16)o0[i];
                oh[4 + i] = (_Float16)o1[i];
            }
            *(f32x4*)&h32[base] = o0;
            *(f32x4*)&h32[base + 4] = o1;
            *(f16x8*)&h16[base] = oh;
        }
        __syncthreads();
    }
}

__global__ void k_pool_seg(const float* __restrict__ h, const int* __restrict__ batch,
                           float* __restrict__ pooled, float* __restrict__ cnt) {
    int lane = threadIdx.x & 63;
    int wid = blockIdx.x * (blockDim.x >> 6) + (threadIdx.x >> 6);
    int nwav = gridDim.x * (blockDim.x >> 6);
    int chunk = (NN + nwav - 1) / nwav;
    int s = wid * chunk;
    if (s >= NN) return;
    int e = s + chunk; if (e > NN) e = NN;
    int g = batch[s];
    float acc = 0.0f, c = 0.0f;
    for (int n = s; n < e; ++n) {
        int b = batch[n];
        if (b != g) {
            atomicAdd(&pooled[g * 64 + lane], acc);
            if (lane == 0) atomicAdd(&cnt[g], c);
            acc = 0.0f; c = 0.0f; g = b;
        }
        acc += h[(size_t)n * 64 + lane];
        c += 1.0f;
    }
    atomicAdd(&pooled[g * 64 + lane], acc);
    if (lane == 0) atomicAdd(&cnt[g], c);
}

__global__ void k_final(const float* __restrict__ pooled, const float* __restrict__ cnt,
                        const float* __restrict__ ow, const float* __restrict__ ob,
                        float* __restrict__ out) {
    __shared__ float red[2];
    int g = blockIdx.x, o = threadIdx.x;  // 128 threads
    float c = fmaxf(cnt[g], 1.0f);
    float acc = ob[o];
#pragma unroll
    for (int j = 0; j < 64; ++j) {
        float pm = fmaxf(pooled[g * 64 + j] / c, 0.0f);
        acc = fmaf(pm, ow[j * 128 + o], acc);
    }
    float ss = acc * acc;
#pragma unroll
    for (int off = 32; off > 0; off >>= 1) ss += __shfl_xor(ss, off);
    if ((o & 63) == 0) red[o >> 6] = ss;
    __syncthreads();
    float nrm = sqrtf(red[0] + red[1]);
    out[g * 128 + o] = acc / fmaxf(nrm, 1e-12f);
}

extern "C" void kernel_launch(void* const* d_in, const int* in_sizes, int n_in,
                              void* d_out, int out_size, void* d_ws, size_t ws_size,
                              hipStream_t stream) {
    const float* x         = (const float*)d_in[0];
    const float* coords_in = (const float*)d_in[1];
    const float* in_w      = (const float*)d_in[2];
    const float* in_b      = (const float*)d_in[3];
    const float* coord_w1  = (const float*)d_in[4];
    const float* coord_b1  = (const float*)d_in[5];
    const float* coord_w2  = (const float*)d_in[6];
    const float* coord_b2  = (const float*)d_in[7];
    const float* ew_w      = (const float*)d_in[8];
    const float* ew_b      = (const float*)d_in[9];
    const float* cn_scale  = (const float*)d_in[10];
    const float* edge_w1   = (const float*)d_in[11];
    const float* edge_b1   = (const float*)d_in[12];
    const float* edge_w2   = (const float*)d_in[13];
    const float* edge_b2   = (const float*)d_in[14];
    const float* node_w1   = (const float*)d_in[15];
    const float* node_b1   = (const float*)d_in[16];
    const float* node_w2   = (const float*)d_in[17];
    const float* node_b2   = (const float*)d_in[18];
    const float* out_w     = (const float*)d_in[19];
    const float* out_b     = (const float*)d_in[20];
    const int* ei          = (const int*)d_in[21];
    const int* batch       = (const int*)d_in[22];
    const int* row = ei;
    const int* col = ei + NE;

    char* wp = (char*)d_ws;
    float* h32    = (float*)wp; wp += (size_t)NN * 64 * 4;
    float* cA     = (float*)wp; wp += (size_t)NN * 3 * 4;
    float* cB     = (float*)wp; wp += (size_t)NN * 3 * 4;
    float* pooled = (float*)wp; wp += (size_t)NG * 64 * 4;
    float* cnt    = (float*)wp; wp += (size_t)NG * 4;
    _Float16* h16  = (_Float16*)wp; wp += (size_t)NN * 64 * 2;
    _Float16* cw1T = (_Float16*)wp; wp += (size_t)NL * SEG0 * 2;
    _Float16* ew1T = (_Float16*)wp; wp += (size_t)NL * SEG1 * 2;
    _Float16* ew2T = (_Float16*)wp; wp += (size_t)NL * SEG2 * 2;
    _Float16* nw1T = (_Float16*)wp; wp += (size_t)NL * SEG3 * 2;
    _Float16* nw2T = (_Float16*)wp; wp += (size_t)NL * SEG4 * 2;
    _Float16* cw2T = (_Float16*)wp; wp += (size_t)NL * SEG5 * 2;
    // CSR region
    int* deg       = (int*)wp;            wp += (size_t)NN * 4;
    int* rowptr    = (int*)wp;            wp += (size_t)(NN + 4) * 4;
    int* pos       = (int*)wp;            wp += (size_t)NN * 4;
    int* rowP      = (int*)wp;            wp += (size_t)NE * 4;
    int* colP      = (int*)wp;            wp += (size_t)NE * 4;
    float4* deltas = (float4*)wp;         wp += (size_t)NE * 16;
    _Float16* emsgS= (_Float16*)wp;       wp += (size_t)NE * 64 * 2;
    size_t csr_need = (size_t)(wp - (char*)d_ws);
    float* agg = (float*)deg;  // legacy path union
    bool use_csr = (ws_size >= csr_need);

    if (use_csr) {
        hipMemsetAsync(deg, 0, (size_t)NN * 4, stream);
        k_hist<<<(NE + 255) / 256, 256, 0, stream>>>(row, deg);
        k_scan<<<1, 256, 0, stream>>>(deg, rowptr);
        hipMemcpyAsync(pos, rowptr, (size_t)NN * 4, hipMemcpyDeviceToDevice, stream);
        k_scatter2<<<(NE + 255) / 256, 256, 0, stream>>>(row, col, pos, rowP, colP);
    }
    k_prep_all<<<(NL * SEGTOT + 255) / 256, 256, 0, stream>>>(
        coord_w1, edge_w1, edge_w2, node_w1, node_w2, coord_w2,
        cw1T, ew1T, ew2T, nw1T, nw2T, cw2T);
    k_init_h<<<(NN * 64 + 255) / 256, 256, 0, stream>>>(x, in_w, in_b, h32, h16);

    const float* cur = coords_in;
    float* nxt = cA;
    for (int l = 0; l < NL; ++l) {
        if (use_csr) {
            k_coord3<1><<<2048, 256, 0, stream>>>(h16, cur, nullptr, rowP, colP, deltas,
                cw1T + (size_t)l * SEG0, coord_b1 + l * 128,
                cw2T + (size_t)l * SEG5, coord_b2 + l * 3,
                ew_w + l * 3, ew_b + l, cn_scale + l);
            k_coord_apply<<<(NN + 255) / 256, 256, 0, stream>>>(cur, nxt, rowptr, deltas);
            k_edge3<1><<<2048, 256, 0, stream>>>(h16, nxt, nullptr, emsgS, rowP, colP,
                ew1T + (size_t)l * SEG1, edge_b1 + l * 128,
                ew2T + (size_t)l * SEG2, edge_b2 + l * 64);
            k_node3<1><<<1024, 256, 0, stream>>>(h32, h16, nullptr, emsgS, rowptr,
                nw1T + (size_t)l * SEG3, node_b1 + l * 128,
                nw2T + (size_t)l * SEG4, node_b2 + l * 64);
        } else {
            hipMemcpyAsync(nxt, cur, (size_t)NN * 3 * sizeof(float), hipMemcpyDeviceToDevice, stream);
            k_coord3<0><<<2048, 256, 0, stream>>>(h16, cur, nxt, row, col, nullptr,
                cw1T + (size_t)l * SEG0, coord_b1 + l * 128,
                cw2T + (size_t)l * SEG5, coord_b2 + l * 3,
                ew_w + l * 3, ew_b + l, cn_scale + l);
            hipMemsetAsync(agg, 0, (size_t)NN * 64 * 4, stream);
            k_edge3<0><<<2048, 256, 0, stream>>>(h16, nxt, agg, nullptr, row, col,
                ew1T + (size_t)l * SEG1, edge_b1 + l * 128,
                ew2T + (size_t)l * SEG2, edge_b2 + l * 64);
            k_node3<0><<<1024, 256, 0, stream>>>(h32, h16, agg, nullptr, nullptr,
                nw1T + (size_t)l * SEG3, node_b1 + l * 128,
                nw2T + (size_t)l * SEG4, node_b2 + l * 64);
        }
        cur = nxt;
        nxt = (nxt == cA) ? cB : cA;
    }
    hipMemsetAsync(pooled, 0, (size_t)(NG * 64 + NG) * sizeof(float), stream);
    k_pool_seg<<<512, 256, 0, stream>>>(h32, batch, pooled, cnt);
    k_final<<<NG, 128, 0, stream>>>(pooled, cnt, out_w, out_b, (float*)d_out);
}

// Round 7
// 1196.489 us; speedup vs baseline: 64.9934x; 1.1250x over previous
//
#include <hip/hip_runtime.h>
#include <math.h>

#define NN 100000
#define NE 1000000
#define NG 64
#define NL 4
#define NT_E (NE / 32)
#define NT_N (NN / 32)

typedef __attribute__((ext_vector_type(8))) _Float16 f16x8;
typedef __attribute__((ext_vector_type(4))) float f32x4;

#define MFMA16(a, b, c) __builtin_amdgcn_mfma_f32_16x16x32_f16(a, b, c, 0, 0, 0)
#define LOG2E 1.44269504088896340f
__device__ __forceinline__ float fsig_(float x) {
    return __builtin_amdgcn_rcpf(1.0f + __builtin_amdgcn_exp2f(-LOG2E * x));
}
__device__ __forceinline__ float fsilu_(float x) { return x * fsig_(x); }

__global__ void k_init_h(const float* __restrict__ x, const float* __restrict__ in_w,
                         const float* __restrict__ in_b, float* __restrict__ h32,
                         _Float16* __restrict__ h16) {
    int idx = blockIdx.x * blockDim.x + threadIdx.x;
    if (idx >= NN * 64) return;
    int n = idx >> 6, j = idx & 63;
    float v = fmaf(x[n], in_w[j], in_b[j]);
    h32[idx] = v;
    h16[idx] = (_Float16)v;
}

// transpose + fp16 + zero-pad all weight families x 4 layers
#define SEG0 21504  // 128*168 cw1T
#define SEG1 21504  // ew1T
#define SEG2 8704   // 64*136  ew2T
#define SEG3 17408  // 128*136 nw1T
#define SEG4 8704   // nw2T
#define SEG5 2176   // 16*136  cw2T (O=3 padded to 16)
#define SEGTOT (SEG0 + SEG1 + SEG2 + SEG3 + SEG4 + SEG5)
__global__ void k_prep_all(const float* __restrict__ cw1, const float* __restrict__ ew1,
                           const float* __restrict__ ew2, const float* __restrict__ nw1,
                           const float* __restrict__ nw2, const float* __restrict__ cw2,
                           _Float16* __restrict__ cw1T, _Float16* __restrict__ ew1T,
                           _Float16* __restrict__ ew2T, _Float16* __restrict__ nw1T,
                           _Float16* __restrict__ nw2T, _Float16* __restrict__ cw2T) {
    int i = blockIdx.x * blockDim.x + threadIdx.x;
    if (i >= NL * SEGTOT) return;
    int l = i / SEGTOT, r = i - l * SEGTOT;
    const float* src; _Float16* dst; int K, O, SD, j;
    if (r < SEG0) { src = cw1 + (size_t)l * 131 * 128; dst = cw1T + (size_t)l * SEG0; K = 131; O = 128; SD = 168; j = r; }
    else if ((r -= SEG0) < SEG1) { src = ew1 + (size_t)l * 131 * 128; dst = ew1T + (size_t)l * SEG1; K = 131; O = 128; SD = 168; j = r; }
    else if ((r -= SEG1) < SEG2) { src = ew2 + (size_t)l * 128 * 64; dst = ew2T + (size_t)l * SEG2; K = 128; O = 64; SD = 136; j = r; }
    else if ((r -= SEG2) < SEG3) { src = nw1 + (size_t)l * 128 * 128; dst = nw1T + (size_t)l * SEG3; K = 128; O = 128; SD = 136; j = r; }
    else if ((r -= SEG3) < SEG4) { src = nw2 + (size_t)l * 128 * 64; dst = nw2T + (size_t)l * SEG4; K = 128; O = 64; SD = 136; j = r; }
    else {
        r -= SEG4;
        const float* s2 = cw2 + (size_t)l * 128 * 3;
        int o = r / 136, k = r - o * 136;
        cw2T[(size_t)l * SEG5 + r] = (o < 3 && k < 128) ? (_Float16)s2[(size_t)k * 3 + o] : (_Float16)0.0f;
        return;
    }
    int o = j / SD, k = j - o * SD;
    dst[j] = (k < K) ? (_Float16)src[(size_t)k * O + o] : (_Float16)0.0f;
}

// ---- CSR build (once per launch) ----
__global__ void k_hist(const int* __restrict__ row, int* __restrict__ deg) {
    int e = blockIdx.x * blockDim.x + threadIdx.x;
    if (e < NE) atomicAdd(&deg[row[e]], 1);
}

// 3-phase parallel exclusive scan of deg[NN] -> rowptr[NN+1]
#define SCB 256          // scan blocks
#define SCT 256          // threads per scan block
#define SCCH ((NN + SCB - 1) / SCB)  // 391 elements per block
__global__ void k_scan_part(const int* __restrict__ deg, int* __restrict__ bsum) {
    __shared__ int red[SCT];
    int b = blockIdx.x;
    int s = b * SCCH, e = min(NN, s + SCCH);
    int sum = 0;
    for (int i = s + threadIdx.x; i < e; i += SCT) sum += deg[i];
    red[threadIdx.x] = sum;
    __syncthreads();
    for (int off = SCT / 2; off > 0; off >>= 1) {
        if (threadIdx.x < off) red[threadIdx.x] += red[threadIdx.x + off];
        __syncthreads();
    }
    if (threadIdx.x == 0) bsum[b] = red[0];
}
__global__ void k_scan_mid(int* __restrict__ bsum) {
    __shared__ int ss[SCB];
    int t = threadIdx.x;
    ss[t] = bsum[t];
    __syncthreads();
    if (t == 0) {
        int run = 0;
        for (int i = 0; i < SCB; ++i) { int v = ss[i]; ss[i] = run; run += v; }
    }
    __syncthreads();
    bsum[t] = ss[t];
}
__global__ void k_scan_fin(const int* __restrict__ deg, const int* __restrict__ bsum,
                           int* __restrict__ rowptr) {
    __shared__ int tsum[SCT];
    int b = blockIdx.x;
    int s = b * SCCH, e = min(NN, s + SCCH);
    const int per = (SCCH + SCT - 1) / SCT;  // 2
    int ts = s + threadIdx.x * per;
    int te = min(e, ts + per);
    int sum = 0;
    for (int i = ts; i < te; ++i) sum += deg[i];
    tsum[threadIdx.x] = sum;
    __syncthreads();
    if (threadIdx.x == 0) {
        int run = bsum[b];
        for (int i = 0; i < SCT; ++i) { int v = tsum[i]; tsum[i] = run; run += v; }
    }
    __syncthreads();
    int run = tsum[threadIdx.x];
    for (int i = ts; i < te; ++i) { rowptr[i] = run; run += deg[i]; }
    if (b == 0 && threadIdx.x == 0) rowptr[NN] = NE;
}

// permute row/col into CSR slot order
__global__ void k_scatter2(const int* __restrict__ row, const int* __restrict__ col,
                           int* __restrict__ pos, int* __restrict__ rowP,
                           int* __restrict__ colP) {
    int e = blockIdx.x * blockDim.x + threadIdx.x;
    if (e < NE) {
        int r = row[e];
        int p = atomicAdd(&pos[r], 1);
        rowP[p] = r;
        colP[p] = col[e];
    }
}

// ---- coord: block-coop GEMM1 + ks-split GEMM2; CSR=1 -> write deltas[slot] coalesced
template <int CSR>
__global__ __launch_bounds__(256)
void k_coord3(const _Float16* __restrict__ h16,
              const float* __restrict__ ccur, float* __restrict__ cnext,
              const int* __restrict__ rowP, const int* __restrict__ colP,
              float4* __restrict__ deltas,
              const _Float16* __restrict__ w1T, const float* __restrict__ b1,
              const _Float16* __restrict__ w2T, const float* __restrict__ b2,
              const float* __restrict__ eww, const float* __restrict__ ewb,
              const float* __restrict__ cns) {
    __shared__ __attribute__((aligned(16))) _Float16 cin[32][168];
    __shared__ __attribute__((aligned(16))) _Float16 h1[32][136];
    __shared__ __attribute__((aligned(16))) float pbuf[4][32][17];
    __shared__ float gate[32];
    for (int i = threadIdx.x; i < 32 * 168; i += 256) (&cin[0][0])[i] = (_Float16)0.0f;
    int tid = threadIdx.x;
    int w = tid >> 6, lane = tid & 63, lc = lane & 15, lg = lane >> 4;
    float e0w = eww[0], e1w = eww[1], e2w = eww[2], ebw = ewb[0], sc = cns[0];
    float b20 = b2[0], b21 = b2[1], b22 = b2[2];
    f16x8 bw1[2][5];
#pragma unroll
    for (int ti = 0; ti < 2; ++ti)
#pragma unroll
        for (int ks = 0; ks < 5; ++ks)
            bw1[ti][ks] = *(const f16x8*)&w1T[(size_t)((2 * w + ti) * 16 + lc) * 168 + ks * 32 + lg * 8];
    f16x8 bw2 = *(const f16x8*)&w2T[(size_t)lc * 136 + w * 32 + lg * 8];
    float bias10 = b1[(2 * w) * 16 + lc], bias11 = b1[(2 * w + 1) * 16 + lc];
    __syncthreads();

    for (int tile = blockIdx.x; tile < NT_E; tile += gridDim.x) {
        int e0 = tile * 32;
        {
            int el = tid >> 3, part = tid & 7;
            int r = rowP[e0 + el], c = colP[e0 + el];
            *(f16x8*)&cin[el][part * 8] = *(const f16x8*)&h16[(size_t)r * 64 + part * 8];
            *(f16x8*)&cin[el][64 + part * 8] = *(const f16x8*)&h16[(size_t)c * 64 + part * 8];
        }
        if (tid < 32) {
            int r = rowP[e0 + tid], c = colP[e0 + tid];
            float rx = ccur[r * 3 + 0] - ccur[c * 3 + 0];
            float ry = ccur[r * 3 + 1] - ccur[c * 3 + 1];
            float rz = ccur[r * 3 + 2] - ccur[c * 3 + 2];
            cin[tid][128] = (_Float16)rx; cin[tid][129] = (_Float16)ry; cin[tid][130] = (_Float16)rz;
            gate[tid] = fsig_(fmaf(rx, e0w, fmaf(ry, e1w, fmaf(rz, e2w, ebw))));
        }
        __syncthreads();
        f32x4 acc[2][2];
        acc[0][0] = acc[0][1] = acc[1][0] = acc[1][1] = (f32x4){0.f, 0.f, 0.f, 0.f};
#pragma unroll
        for (int ks = 0; ks < 5; ++ks) {
            f16x8 a0 = *(const f16x8*)&cin[lc][ks * 32 + lg * 8];
            f16x8 a1 = *(const f16x8*)&cin[16 + lc][ks * 32 + lg * 8];
#pragma unroll
            for (int ti = 0; ti < 2; ++ti) {
                acc[0][ti] = MFMA16(a0, bw1[ti][ks], acc[0][ti]);
                acc[1][ti] = MFMA16(a1, bw1[ti][ks], acc[1][ti]);
            }
        }
#pragma unroll
        for (int ti = 0; ti < 2; ++ti) {
            int colc = (2 * w + ti) * 16 + lc;
            float bias = ti ? bias11 : bias10;
#pragma unroll
            for (int rt = 0; rt < 2; ++rt)
#pragma unroll
                for (int j = 0; j < 4; ++j)
                    h1[rt * 16 + lg * 4 + j][colc] = (_Float16)fsilu_(acc[rt][ti][j] + bias);
        }
        __syncthreads();
        f32x4 c2[2];
        c2[0] = c2[1] = (f32x4){0.f, 0.f, 0.f, 0.f};
        {
            f16x8 a0 = *(const f16x8*)&h1[lc][w * 32 + lg * 8];
            f16x8 a1 = *(const f16x8*)&h1[16 + lc][w * 32 + lg * 8];
            c2[0] = MFMA16(a0, bw2, c2[0]);
            c2[1] = MFMA16(a1, bw2, c2[1]);
        }
#pragma unroll
        for (int rt = 0; rt < 2; ++rt)
#pragma unroll
            for (int j = 0; j < 4; ++j)
                pbuf[w][rt * 16 + lg * 4 + j][lc] = c2[rt][j];
        __syncthreads();
        if (tid < 32) {
            float d0 = pbuf[0][tid][0] + pbuf[1][tid][0] + pbuf[2][tid][0] + pbuf[3][tid][0] + b20;
            float d1 = pbuf[0][tid][1] + pbuf[1][tid][1] + pbuf[2][tid][1] + pbuf[3][tid][1] + b21;
            float d2 = pbuf[0][tid][2] + pbuf[1][tid][2] + pbuf[2][tid][2] + pbuf[3][tid][2] + b22;
            float ss = d0 * d0 + d1 * d1 + d2 * d2;
            float nrm = fmaxf(__builtin_amdgcn_sqrtf(ss), 1e-8f);
            float m = sc * __builtin_amdgcn_rcpf(nrm) * gate[tid];
            if (CSR) {
                deltas[e0 + tid] = make_float4(d0 * m, d1 * m, d2 * m, 0.0f);
            } else {
                int r = rowP[e0 + tid];
                atomicAdd(&cnext[(size_t)r * 3 + 0], d0 * m);
                atomicAdd(&cnext[(size_t)r * 3 + 1], d1 * m);
                atomicAdd(&cnext[(size_t)r * 3 + 2], d2 * m);
            }
        }
    }
}

// cnext[n] = ccur[n] + sum of this node's contiguous delta slots (no atomics)
__global__ void k_coord_apply(const float* __restrict__ ccur, float* __restrict__ cnext,
                              const int* __restrict__ rowptr,
                              const float4* __restrict__ deltas) {
    int n = blockIdx.x * blockDim.x + threadIdx.x;
    if (n >= NN) return;
    int s = rowptr[n], e = rowptr[n + 1];
    float d0 = 0.f, d1 = 0.f, d2 = 0.f;
    for (int j = s; j < e; ++j) {
        float4 d = deltas[j];
        d0 += d.x; d1 += d.y; d2 += d.z;
    }
    cnext[(size_t)n * 3 + 0] = ccur[(size_t)n * 3 + 0] + d0;
    cnext[(size_t)n * 3 + 1] = ccur[(size_t)n * 3 + 1] + d1;
    cnext[(size_t)n * 3 + 2] = ccur[(size_t)n * 3 + 2] + d2;
}

// ---- edge: CSR=1 -> write emsgS[slot] coalesced; CSR=0 -> atomic agg
template <int CSR>
__global__ __launch_bounds__(256)
void k_edge3(const _Float16* __restrict__ h16, const float* __restrict__ coords,
             float* __restrict__ agg, _Float16* __restrict__ emsgS,
             const int* __restrict__ rowP, const int* __restrict__ colP,
             const _Float16* __restrict__ w1T, const float* __restrict__ b1,
             const _Float16* __restrict__ w2T, const float* __restrict__ b2) {
    __shared__ __attribute__((aligned(16))) _Float16 cin[32][168];
    __shared__ __attribute__((aligned(16))) _Float16 h1[32][136];
    __shared__ __attribute__((aligned(16))) _Float16 msg[32][72];
    for (int i = threadIdx.x; i < 32 * 168; i += 256) (&cin[0][0])[i] = (_Float16)0.0f;
    int tid = threadIdx.x;
    int w = tid >> 6, lane = tid & 63, lc = lane & 15, lg = lane >> 4;
    f16x8 bw1[2][5];
#pragma unroll
    for (int ti = 0; ti < 2; ++ti)
#pragma unroll
        for (int ks = 0; ks < 5; ++ks)
            bw1[ti][ks] = *(const f16x8*)&w1T[(size_t)((2 * w + ti) * 16 + lc) * 168 + ks * 32 + lg * 8];
    f16x8 bw2[4];
#pragma unroll
    for (int ks = 0; ks < 4; ++ks)
        bw2[ks] = *(const f16x8*)&w2T[(size_t)(w * 16 + lc) * 136 + ks * 32 + lg * 8];
    float bias10 = b1[(2 * w) * 16 + lc], bias11 = b1[(2 * w + 1) * 16 + lc];
    float bias2 = b2[w * 16 + lc];
    __syncthreads();

    for (int tile = blockIdx.x; tile < NT_E; tile += gridDim.x) {
        int e0 = tile * 32;
        {
            int el = tid >> 3, part = tid & 7;
            int r = rowP[e0 + el], c = colP[e0 + el];
            *(f16x8*)&cin[el][part * 8] = *(const f16x8*)&h16[(size_t)r * 64 + part * 8];
            *(f16x8*)&cin[el][64 + part * 8] = *(const f16x8*)&h16[(size_t)c * 64 + part * 8];
        }
        if (tid < 32) {
            int r = rowP[e0 + tid], c = colP[e0 + tid];
            cin[tid][128] = (_Float16)(coords[r * 3 + 0] - coords[c * 3 + 0]);
            cin[tid][129] = (_Float16)(coords[r * 3 + 1] - coords[c * 3 + 1]);
            cin[tid][130] = (_Float16)(coords[r * 3 + 2] - coords[c * 3 + 2]);
        }
        __syncthreads();
        f32x4 acc[2][2];
        acc[0][0] = acc[0][1] = acc[1][0] = acc[1][1] = (f32x4){0.f, 0.f, 0.f, 0.f};
#pragma unroll
        for (int ks = 0; ks < 5; ++ks) {
            f16x8 a0 = *(const f16x8*)&cin[lc][ks * 32 + lg * 8];
            f16x8 a1 = *(const f16x8*)&cin[16 + lc][ks * 32 + lg * 8];
#pragma unroll
            for (int ti = 0; ti < 2; ++ti) {
                acc[0][ti] = MFMA16(a0, bw1[ti][ks], acc[0][ti]);
                acc[1][ti] = MFMA16(a1, bw1[ti][ks], acc[1][ti]);
            }
        }
#pragma unroll
        for (int ti = 0; ti < 2; ++ti) {
            int colc = (2 * w + ti) * 16 + lc;
            float bias = ti ? bias11 : bias10;
#pragma unroll
            for (int rt = 0; rt < 2; ++rt)
#pragma unroll
                for (int j = 0; j < 4; ++j)
                    h1[rt * 16 + lg * 4 + j][colc] = (_Float16)fsilu_(acc[rt][ti][j] + bias);
        }
        __syncthreads();
        f32x4 c2[2];
        c2[0] = c2[1] = (f32x4){0.f, 0.f, 0.f, 0.f};
#pragma unroll
        for (int ks = 0; ks < 4; ++ks) {
            f16x8 a0 = *(const f16x8*)&h1[lc][ks * 32 + lg * 8];
            f16x8 a1 = *(const f16x8*)&h1[16 + lc][ks * 32 + lg * 8];
            c2[0] = MFMA16(a0, bw2[ks], c2[0]);
            c2[1] = MFMA16(a1, bw2[ks], c2[1]);
        }
        if (CSR) {
#pragma unroll
            for (int rt = 0; rt < 2; ++rt)
#pragma unroll
                for (int j = 0; j < 4; ++j)
                    msg[rt * 16 + lg * 4 + j][w * 16 + lc] = (_Float16)fsilu_(c2[rt][j] + bias2);
            __syncthreads();
            int r = tid >> 3, part = tid & 7;
            *(f16x8*)&emsgS[(size_t)(e0 + r) * 64 + part * 8] = *(const f16x8*)&msg[r][part * 8];
        } else {
#pragma unroll
            for (int rt = 0; rt < 2; ++rt)
#pragma unroll
                for (int j = 0; j < 4; ++j)
                    atomicAdd(&agg[(size_t)rowP[e0 + rt * 16 + lg * 4 + j] * 64 + w * 16 + lc],
                              fsilu_(c2[rt][j] + bias2));
            __syncthreads();
        }
    }
}

// ---- node: CSR=1 -> contiguous emsgS range per node; else agg read
template <int CSR>
__global__ __launch_bounds__(256)
void k_node3(float* __restrict__ h32, _Float16* __restrict__ h16,
             const float* __restrict__ agg, const _Float16* __restrict__ emsgS,
             const int* __restrict__ rowptr,
             const _Float16* __restrict__ w1T, const float* __restrict__ b1,
             const _Float16* __restrict__ w2T, const float* __restrict__ b2) {
    __shared__ __attribute__((aligned(16))) _Float16 cin[32][136];
    __shared__ __attribute__((aligned(16))) _Float16 h1[32][136];
    __shared__ __attribute__((aligned(16))) float vbuf[32][64];
    int tid = threadIdx.x;
    int w = tid >> 6, lane = tid & 63, lc = lane & 15, lg = lane >> 4;
    f16x8 bw1[2][4], bw2[4];
#pragma unroll
    for (int ti = 0; ti < 2; ++ti)
#pragma unroll
        for (int ks = 0; ks < 4; ++ks)
            bw1[ti][ks] = *(const f16x8*)&w1T[(size_t)((2 * w + ti) * 16 + lc) * 136 + ks * 32 + lg * 8];
#pragma unroll
    for (int ks = 0; ks < 4; ++ks)
        bw2[ks] = *(const f16x8*)&w2T[(size_t)(w * 16 + lc) * 136 + ks * 32 + lg * 8];
    float bias10 = b1[(2 * w) * 16 + lc], bias11 = b1[(2 * w + 1) * 16 + lc];
    float bias2 = b2[w * 16 + lc];

    for (int tile = blockIdx.x; tile < NT_N; tile += gridDim.x) {
        int n0 = tile * 32;
        {
            int nl = tid >> 3, part = tid & 7;
            int n = n0 + nl;
            *(f16x8*)&cin[nl][part * 8] = *(const f16x8*)&h16[(size_t)n * 64 + part * 8];
            if (CSR) {
                float a[8] = {0.f, 0.f, 0.f, 0.f, 0.f, 0.f, 0.f, 0.f};
                int s = rowptr[n], e = rowptr[n + 1];
                for (int jj = s; jj < e; ++jj) {
                    f16x8 m = *(const f16x8*)&emsgS[(size_t)jj * 64 + part * 8];
#pragma unroll
                    for (int q = 0; q < 8; ++q) a[q] += (float)m[q];
                }
                f16x8 o;
#pragma unroll
                for (int q = 0; q < 8; ++q) o[q] = (_Float16)a[q];
                *(f16x8*)&cin[nl][64 + part * 8] = o;
            } else {
                f32x4 xx = *(const f32x4*)&agg[(size_t)n * 64 + part * 8];
                f32x4 yy = *(const f32x4*)&agg[(size_t)n * 64 + part * 8 + 4];
                f16x8 o;
                o[0] = (_Float16)xx[0]; o[1] = (_Float16)xx[1]; o[2] = (_Float16)xx[2]; o[3] = (_Float16)xx[3];
                o[4] = (_Float16)yy[0]; o[5] = (_Float16)yy[1]; o[6] = (_Float16)yy[2]; o[7] = (_Float16)yy[3];
                *(f16x8*)&cin[nl][64 + part * 8] = o;
            }
        }
        __syncthreads();
        f32x4 acc[2][2];
        acc[0][0] = acc[0][1] = acc[1][0] = acc[1][1] = (f32x4){0.f, 0.f, 0.f, 0.f};
#pragma unroll
        for (int ks = 0; ks < 4; ++ks) {
            f16x8 a0 = *(const f16x8*)&cin[lc][ks * 32 + lg * 8];
            f16x8 a1 = *(const f16x8*)&cin[16 + lc][ks * 32 + lg * 8];
#pragma unroll
            for (int ti = 0; ti < 2; ++ti) {
                acc[0][ti] = MFMA16(a0, bw1[ti][ks], acc[0][ti]);
                acc[1][ti] = MFMA16(a1, bw1[ti][ks], acc[1][ti]);
            }
        }
#pragma unroll
        for (int ti = 0; ti < 2; ++ti) {
            int colc = (2 * w + ti) * 16 + lc;
            float bias = ti ? bias11 : bias10;
#pragma unroll
            for (int rt = 0; rt < 2; ++rt)
#pragma unroll
                for (int j = 0; j < 4; ++j)
                    h1[rt * 16 + lg * 4 + j][colc] = (_Float16)fsilu_(acc[rt][ti][j] + bias);
        }
        __syncthreads();
        f32x4 c2[2];
        c2[0] = c2[1] = (f32x4){0.f, 0.f, 0.f, 0.f};
#pragma unroll
        for (int ks = 0; ks < 4; ++ks) {
            f16x8 a0 = *(const f16x8*)&h1[lc][ks * 32 + lg * 8];
            f16x8 a1 = *(const f16x8*)&h1[16 + lc][ks * 32 + lg * 8];
            c2[0] = MFMA16(a0, bw2[ks], c2[0]);
            c2[1] = MFMA16(a1, bw2[ks], c2[1]);
        }
#pragma unroll
        for (int rt = 0; rt < 2; ++rt)
#pragma unroll
            for (int j = 0; j < 4; ++j) {
                int rl = rt * 16 + lg * 4 + j, colc = w * 16 + lc;
                vbuf[rl][colc] = h32[(size_t)(n0 + rl) * 64 + colc] + c2[rt][j] + bias2;
            }
        __syncthreads();
        {
            int r = w * 8 + (lane >> 3), sub = lane & 7;
            f32x4 v0 = *(const f32x4*)&vbuf[r][sub * 8];
            f32x4 v1 = *(const f32x4*)&vbuf[r][sub * 8 + 4];
            float s = v0[0] + v0[1] + v0[2] + v0[3] + v1[0] + v1[1] + v1[2] + v1[3];
            float sq = v0[0]*v0[0] + v0[1]*v0[1] + v0[2]*v0[2] + v0[3]*v0[3]
                     + v1[0]*v1[0] + v1[1]*v1[1] + v1[2]*v1[2] + v1[3]*v1[3];
            s += __shfl_xor(s, 1); s += __shfl_xor(s, 2); s += __shfl_xor(s, 4);
            sq += __shfl_xor(sq, 1); sq += __shfl_xor(sq, 2); sq += __shfl_xor(sq, 4);
            float mu = s * (1.0f / 64.0f);
            float var = sq * (1.0f / 64.0f) - mu * mu;
            float rs = __builtin_amdgcn_rcpf(__builtin_amdgcn_sqrtf(var + 1e-5f));
            size_t base = (size_t)(n0 + r) * 64 + sub * 8;
            f32x4 o0, o1; f16x8 oh;
#pragma unroll
            for (int i = 0; i < 4; ++i) {
                o0[i] = (v0[i] - mu) * rs;
                o1[i] = (v1[i] - mu) * rs;
                oh[i] = (_Float16)o0[i];
                oh[4 + i] = (_Float16)o1[i];
            }
            *(f32x4*)&h32[base] = o0;
            *(f32x4*)&h32[base + 4] = o1;
            *(f16x8*)&h16[base] = oh;
        }
        __syncthreads();
    }
}

__global__ void k_pool_seg(const float* __restrict__ h, const int* __restrict__ batch,
                           float* __restrict__ pooled, float* __restrict__ cnt) {
    int lane = threadIdx.x & 63;
    int wid = blockIdx.x * (blockDim.x >> 6) + (threadIdx.x >> 6);
    int nwav = gridDim.x * (blockDim.x >> 6);
    int chunk = (NN + nwav - 1) / nwav;
    int s = wid * chunk;
    if (s >= NN) return;
    int e = s + chunk; if (e > NN) e = NN;
    int g = batch[s];
    float acc = 0.0f, c = 0.0f;
    for (int n = s; n < e; ++n) {
        int b = batch[n];
        if (b != g) {
            atomicAdd(&pooled[g * 64 + lane], acc);
            if (lane == 0) atomicAdd(&cnt[g], c);
            acc = 0.0f; c = 0.0f; g = b;
        }
        acc += h[(size_t)n * 64 + lane];
        c += 1.0f;
    }
    atomicAdd(&pooled[g * 64 + lane], acc);
    if (lane == 0) atomicAdd(&cnt[g], c);
}

__global__ void k_final(const float* __restrict__ pooled, const float* __restrict__ cnt,
                        const float* __restrict__ ow, const float* __restrict__ ob,
                        float* __restrict__ out) {
    __shared__ float red[2];
    int g = blockIdx.x, o = threadIdx.x;  // 128 threads
    float c = fmaxf(cnt[g], 1.0f);
    float acc = ob[o];
#pragma unroll
    for (int j = 0; j < 64; ++j) {
        float pm = fmaxf(pooled[g * 64 + j] / c, 0.0f);
        acc = fmaf(pm, ow[j * 128 + o], acc);
    }
    float ss = acc * acc;
#pragma unroll
    for (int off = 32; off > 0; off >>= 1) ss += __shfl_xor(ss, off);
    if ((o & 63) == 0) red[o >> 6] = ss;
    __syncthreads();
    float nrm = sqrtf(red[0] + red[1]);
    out[g * 128 + o] = acc / fmaxf(nrm, 1e-12f);
}

extern "C" void kernel_launch(void* const* d_in, const int* in_sizes, int n_in,
                              void* d_out, int out_size, void* d_ws, size_t ws_size,
                              hipStream_t stream) {
    const float* x         = (const float*)d_in[0];
    const float* coords_in = (const float*)d_in[1];
    const float* in_w      = (const float*)d_in[2];
    const float* in_b      = (const float*)d_in[3];
    const float* coord_w1  = (const float*)d_in[4];
    const float* coord_b1  = (const float*)d_in[5];
    const float* coord_w2  = (const float*)d_in[6];
    const float* coord_b2  = (const float*)d_in[7];
    const float* ew_w      = (const float*)d_in[8];
    const float* ew_b      = (const float*)d_in[9];
    const float* cn_scale  = (const float*)d_in[10];
    const float* edge_w1   = (const float*)d_in[11];
    const float* edge_b1   = (const float*)d_in[12];
    const float* edge_w2   = (const float*)d_in[13];
    const float* edge_b2   = (const float*)d_in[14];
    const float* node_w1   = (const float*)d_in[15];
    const float* node_b1   = (const float*)d_in[16];
    const float* node_w2   = (const float*)d_in[17];
    const float* node_b2   = (const float*)d_in[18];
    const float* out_w     = (const float*)d_in[19];
    const float* out_b     = (const float*)d_in[20];
    const int* ei          = (const int*)d_in[21];
    const int* batch       = (const int*)d_in[22];
    const int* row = ei;
    const int* col = ei + NE;

    char* wp = (char*)d_ws;
    float* h32    = (float*)wp; wp += (size_t)NN * 64 * 4;
    float* cA     = (float*)wp; wp += (size_t)NN * 3 * 4;
    float* cB     = (float*)wp; wp += (size_t)NN * 3 * 4;
    float* pooled = (float*)wp; wp += (size_t)NG * 64 * 4;
    float* cnt    = (float*)wp; wp += (size_t)NG * 4;
    _Float16* h16  = (_Float16*)wp; wp += (size_t)NN * 64 * 2;
    _Float16* cw1T = (_Float16*)wp; wp += (size_t)NL * SEG0 * 2;
    _Float16* ew1T = (_Float16*)wp; wp += (size_t)NL * SEG1 * 2;
    _Float16* ew2T = (_Float16*)wp; wp += (size_t)NL * SEG2 * 2;
    _Float16* nw1T = (_Float16*)wp; wp += (size_t)NL * SEG3 * 2;
    _Float16* nw2T = (_Float16*)wp; wp += (size_t)NL * SEG4 * 2;
    _Float16* cw2T = (_Float16*)wp; wp += (size_t)NL * SEG5 * 2;
    // CSR region
    int* deg       = (int*)wp;            wp += (size_t)NN * 4;
    int* rowptr    = (int*)wp;            wp += (size_t)(NN + 4) * 4;
    int* pos       = (int*)wp;            wp += (size_t)NN * 4;
    int* bsum      = (int*)wp;            wp += (size_t)SCB * 4;
    int* rowP      = (int*)wp;            wp += (size_t)NE * 4;
    int* colP      = (int*)wp;            wp += (size_t)NE * 4;
    float4* deltas = (float4*)wp;         wp += (size_t)NE * 16;
    _Float16* emsgS= (_Float16*)wp;       wp += (size_t)NE * 64 * 2;
    size_t csr_need = (size_t)(wp - (char*)d_ws);
    float* agg = (float*)deg;  // legacy path union
    bool use_csr = (ws_size >= csr_need);

    if (use_csr) {
        hipMemsetAsync(deg, 0, (size_t)NN * 4, stream);
        k_hist<<<(NE + 255) / 256, 256, 0, stream>>>(row, deg);
        k_scan_part<<<SCB, SCT, 0, stream>>>(deg, bsum);
        k_scan_mid<<<1, SCB, 0, stream>>>(bsum);
        k_scan_fin<<<SCB, SCT, 0, stream>>>(deg, bsum, rowptr);
        hipMemcpyAsync(pos, rowptr, (size_t)NN * 4, hipMemcpyDeviceToDevice, stream);
        k_scatter2<<<(NE + 255) / 256, 256, 0, stream>>>(row, col, pos, rowP, colP);
    }
    k_prep_all<<<(NL * SEGTOT + 255) / 256, 256, 0, stream>>>(
        coord_w1, edge_w1, edge_w2, node_w1, node_w2, coord_w2,
        cw1T, ew1T, ew2T, nw1T, nw2T, cw2T);
    k_init_h<<<(NN * 64 + 255) / 256, 256, 0, stream>>>(x, in_w, in_b, h32, h16);

    const float* cur = coords_in;
    float* nxt = cA;
    for (int l = 0; l < NL; ++l) {
        if (use_csr) {
            k_coord3<1><<<2048, 256, 0, stream>>>(h16, cur, nullptr, rowP, colP, deltas,
                cw1T + (size_t)l * SEG0, coord_b1 + l * 128,
                cw2T + (size_t)l * SEG5, coord_b2 + l * 3,
                ew_w + l * 3, ew_b + l, cn_scale + l);
            k_coord_apply<<<(NN + 255) / 256, 256, 0, stream>>>(cur, nxt, rowptr, deltas);
            k_edge3<1><<<2048, 256, 0, stream>>>(h16, nxt, nullptr, emsgS, rowP, colP,
                ew1T + (size_t)l * SEG1, edge_b1 + l * 128,
                ew2T + (size_t)l * SEG2, edge_b2 + l * 64);
            k_node3<1><<<1024, 256, 0, stream>>>(h32, h16, nullptr, emsgS, rowptr,
                nw1T + (size_t)l * SEG3, node_b1 + l * 128,
                nw2T + (size_t)l * SEG4, node_b2 + l * 64);
        } else {
            hipMemcpyAsync(nxt, cur, (size_t)NN * 3 * sizeof(float), hipMemcpyDeviceToDevice, stream);
            k_coord3<0><<<2048, 256, 0, stream>>>(h16, cur, nxt, row, col, nullptr,
                cw1T + (size_t)l * SEG0, coord_b1 + l * 128,
                cw2T + (size_t)l * SEG5, coord_b2 + l * 3,
                ew_w + l * 3, ew_b + l, cn_scale + l);
            hipMemsetAsync(agg, 0, (size_t)NN * 64 * 4, stream);
            k_edge3<0><<<2048, 256, 0, stream>>>(h16, nxt, agg, nullptr, row, col,
                ew1T + (size_t)l * SEG1, edge_b1 + l * 128,
                ew2T + (size_t)l * SEG2, edge_b2 + l * 64);
            k_node3<0><<<1024, 256, 0, stream>>>(h32, h16, agg, nullptr, nullptr,
                nw1T + (size_t)l * SEG3, node_b1 + l * 128,
                nw2T + (size_t)l * SEG4, node_b2 + l * 64);
        }
        cur = nxt;
        nxt = (nxt == cA) ? cB : cA;
    }
    hipMemsetAsync(pooled, 0, (size_t)(NG * 64 + NG) * sizeof(float), stream);
    k_pool_seg<<<512, 256, 0, stream>>>(h32, batch, pooled, cnt);
    k_final<<<NG, 128, 0, stream>>>(pooled, cnt, out_w, out_b, (float*)d_out);
}